// Round 15
// baseline (435.814 us; speedup 1.0000x reference)
//
#include <hip/hip_runtime.h>
#include <cstdint>
#include <cstddef>

// ---------- types ----------
typedef float f32x4 __attribute__((ext_vector_type(4)));
typedef short bf16x8 __attribute__((ext_vector_type(8)));

typedef __attribute__((address_space(1))) void void_g;
typedef __attribute__((address_space(3))) void void_l;

__device__ __forceinline__ void gld16(const void* g, void* l) {
  // async global->LDS, 16B per lane; LDS dest = wave-uniform base + lane*16
  __builtin_amdgcn_global_load_lds((void_g*)g, (void_l*)l, 16, 0, 0);
}

__device__ __forceinline__ unsigned short f2b(float f) {
  union { float f; uint32_t u; } c; c.f = f;
  uint32_t u = c.u;
  return (unsigned short)((u + 0x7fffu + ((u >> 16) & 1u)) >> 16);  // RNE
}

__device__ __forceinline__ uint32_t cvtpk(float lo, float hi) {
  uint32_t r;
  asm("v_cvt_pk_bf16_f32 %0, %1, %2" : "=v"(r) : "v"(lo), "v"(hi));
  return r;  // low16 = bf16(lo), high16 = bf16(hi)
}

__device__ __forceinline__ float exp2_fast(float x) {
  return __builtin_exp2f(x);  // lowers to v_exp_f32 (2^x) on gfx950
}

// ---------- all weight casts fp32 -> bf16 in one launch ----------
__global__ __launch_bounds__(256) void cast_all(const float* __restrict__ w1,
                                                const float* __restrict__ w2,
                                                const float* __restrict__ wq,
                                                const float* __restrict__ wk,
                                                const float* __restrict__ wv,
                                                const float* __restrict__ wo,
                                                unsigned short* __restrict__ d1,
                                                unsigned short* __restrict__ d2,
                                                unsigned short* __restrict__ dqk,
                                                unsigned short* __restrict__ dv,
                                                unsigned short* __restrict__ dod) {
  int blk = blockIdx.x;
  const float* s;
  unsigned short* d;
  int off;
  if (blk < 4096) { s = w1; d = d1; off = blk; }
  else if (blk < 8192) { s = w2; d = d2; off = blk - 4096; }
  else if (blk < 9216) { s = wq; d = dqk; off = blk - 8192; }
  else if (blk < 10240) { s = wk; d = dqk + (1 << 20); off = blk - 9216; }
  else if (blk < 11264) { s = wv; d = dv; off = blk - 10240; }
  else { s = wo; d = dod; off = blk - 11264; }
  int i = off * 256 + threadIdx.x;
  float4 v = ((const float4*)s)[i];
  ushort4 o;
  o.x = f2b(v.x); o.y = f2b(v.y); o.z = f2b(v.z); o.w = f2b(v.w);
  ((ushort4*)d)[i] = o;
}

// ---------- LayerNorm (unbiased std, scalar alpha/beta) -> bf16 ----------
__global__ __launch_bounds__(256) void ln_bf16(const float* __restrict__ X,
                                               unsigned short* __restrict__ out,
                                               const float* __restrict__ alpha,
                                               const float* __restrict__ beta) {
  int row = blockIdx.x;
  int tid = threadIdx.x;
  float4 v = ((const float4*)(X + (size_t)row * 1024))[tid];
  float s = v.x + v.y + v.z + v.w;
  float q = v.x * v.x + v.y * v.y + v.z * v.z + v.w * v.w;
#pragma unroll
  for (int m = 1; m < 64; m <<= 1) { s += __shfl_xor(s, m); q += __shfl_xor(q, m); }
  __shared__ float red[8];
  int wave = tid >> 6;
  if ((tid & 63) == 0) { red[wave] = s; red[4 + wave] = q; }
  __syncthreads();
  s = red[0] + red[1] + red[2] + red[3];
  q = red[4] + red[5] + red[6] + red[7];
  float mean = s * (1.0f / 1024.0f);
  float var = fmaxf((q - 1024.0f * mean * mean) * (1.0f / 1023.0f), 0.0f);
  float inv = alpha[0] / (sqrtf(var) + 1e-6f);
  float b = beta[0];
  ushort4 o;
  o.x = f2b((v.x - mean) * inv + b);
  o.y = f2b((v.y - mean) * inv + b);
  o.z = f2b((v.z - mean) * inv + b);
  o.w = f2b((v.w - mean) * inv + b);
  ((ushort4*)(out + (size_t)row * 1024))[tid] = o;
}

// ---------- GEMM 256x256 8-wave, BK=64, counted-vmcnt + frag-prefetch pipeline ----------
template <int RELU, int BIAS2>
__global__ __launch_bounds__(512, 1) void gemm256(const unsigned short* __restrict__ A,
                                                  const unsigned short* __restrict__ W,
                                                  const float* __restrict__ bias,
                                                  const float* __restrict__ bias2, int b2off,
                                                  unsigned short* __restrict__ outB,
                                                  int M, int N, int K, int sA, int sW) {
  __shared__ unsigned short lds[2][4][128 * 64];  // 128 KB
  int nbn = N >> 8;
  int nwg = gridDim.x;
  int bid = blockIdx.x;
  int wg = (bid & 7) * (nwg >> 3) + (bid >> 3);  // XCD swizzle (nwg % 8 == 0)
  int tm = wg / nbn, tn = wg % nbn;
  int tid = threadIdx.x;
  int wave = tid >> 6, lane = tid & 63;
  int wr = wave >> 2, wc = wave & 3;  // 2 x 4 wave grid; per-wave C = 128 x 64
  int l15 = lane & 15, g = lane >> 4;
  int nt = K >> 6;

  const unsigned short* Abase = A + (size_t)(tm * 256) * sA;
  const unsigned short* Wbase = W + (size_t)(tn * 256) * sW;
  int srow = tid >> 3;
  int schunk = (tid & 7) ^ (srow & 7);

  f32x4 acc[8][4] = {};
  bf16x8 afrA[2][2], afrB[2][2], bfr[2][4];

  auto stage = [&](int buf, int s, int kt) {
    const unsigned short* base = (s < 2) ? Abase : Wbase;
    int str = (s < 2) ? sA : sW;
    int rbase = (s & 1) * 128;
#pragma unroll
    for (int e = 0; e < 2; ++e) {
      gld16(base + (size_t)(rbase + srow + e * 64) * str + kt * 64 + schunk * 8,
            &lds[buf][s][wave * 512 + e * 4096]);
    }
  };
  auto readB = [&](int buf) {
    const unsigned short* Bh = &lds[buf][2 + (wc >> 1)][0];
#pragma unroll
    for (int kk = 0; kk < 2; ++kk)
#pragma unroll
      for (int j = 0; j < 4; ++j) {
        int br = (wc & 1) * 64 + j * 16 + l15;
        bfr[kk][j] = *(const bf16x8*)&Bh[br * 64 + (((kk * 4 + g) ^ (br & 7)) * 8)];
      }
  };
  auto readA = [&](bf16x8 (&dst)[2][2], int buf, int q) {
    const unsigned short* Ah = &lds[buf][wr][0];
#pragma unroll
    for (int kk = 0; kk < 2; ++kk)
#pragma unroll
      for (int ri = 0; ri < 2; ++ri) {
        int ar = q * 32 + ri * 16 + l15;
        dst[kk][ri] = *(const bf16x8*)&Ah[ar * 64 + (((kk * 4 + g) ^ (ar & 7)) * 8)];
      }
  };
  auto mfma16 = [&](bf16x8 (&af)[2][2], int q) {
    __builtin_amdgcn_s_setprio(1);
#pragma unroll
    for (int kk = 0; kk < 2; ++kk)
#pragma unroll
      for (int ri = 0; ri < 2; ++ri)
#pragma unroll
        for (int j = 0; j < 4; ++j)
          acc[q * 2 + ri][j] = __builtin_amdgcn_mfma_f32_16x16x32_bf16(
              af[kk][ri], bfr[kk][j], acc[q * 2 + ri][j], 0, 0, 0);
    __builtin_amdgcn_s_setprio(0);
  };

  stage(0, 2, 0); stage(0, 3, 0); stage(0, 0, 0); stage(0, 1, 0);
  stage(1, 2, 1); stage(1, 3, 1);
  asm volatile("s_waitcnt vmcnt(4)" ::: "memory");
  __builtin_amdgcn_s_barrier();

  for (int t = 0; t < nt; ++t) {
    int buf = t & 1;
    // phase 0: B frags + afrA(q0) + prefetch afrB(q1)
    __builtin_amdgcn_sched_barrier(0);
    if (t + 1 < nt) stage(buf ^ 1, 0, t + 1);
    readB(buf);
    readA(afrA, buf, 0);
    readA(afrB, buf, 1);
    mfma16(afrA, 0);
    __builtin_amdgcn_s_barrier();
    // phase 1: prefetch afrA(q2)
    __builtin_amdgcn_sched_barrier(0);
    if (t + 1 < nt) stage(buf ^ 1, 1, t + 1);
    readA(afrA, buf, 2);
    mfma16(afrB, 1);
    __builtin_amdgcn_s_barrier();
    // phase 2: prefetch afrB(q3)
    __builtin_amdgcn_sched_barrier(0);
    if (t + 2 < nt) stage(buf, 2, t + 2);
    readA(afrB, buf, 3);
    mfma16(afrA, 2);
    __builtin_amdgcn_s_barrier();
    // phase 3: no ds_reads; MFMA covers vmcnt drain
    __builtin_amdgcn_sched_barrier(0);
    if (t + 2 < nt) stage(buf, 3, t + 2);
    mfma16(afrB, 3);
    if (t + 2 < nt) asm volatile("s_waitcnt vmcnt(4)" ::: "memory");
    else asm volatile("s_waitcnt vmcnt(0)" ::: "memory");
    __builtin_amdgcn_s_barrier();
  }

  int row0 = tm * 256 + wr * 128 + g * 4;
  int col0 = tn * 256 + wc * 64 + l15;
#pragma unroll
  for (int i = 0; i < 8; ++i) {
#pragma unroll
    for (int j = 0; j < 4; ++j) {
      int col = col0 + j * 16;
      float bb = (BIAS2 && col >= b2off) ? bias2[col - b2off] : bias[col];
#pragma unroll
      for (int r = 0; r < 4; ++r) {
        int row = row0 + i * 16 + r;
        float v = acc[i][j][r] + bb;
        if (RELU) v = fmaxf(v, 0.0f);
        outB[(size_t)row * N + col] = f2b(v);
      }
    }
  }
}

// ---------- GEMM 256x128 8-wave, BK=64, counted-vmcnt + frag-prefetch ----------
// MODE: 1 = bf16 out + row bias; 2 = fp32 out = resid + v + col bias; 3 = fp32 out += v.
template <int MODE>
__global__ __launch_bounds__(512, 1) void gemm256x128(const unsigned short* __restrict__ A,
                                                      const unsigned short* __restrict__ W,
                                                      const float* __restrict__ bias,
                                                      const float* __restrict__ resid,
                                                      float* __restrict__ outF,
                                                      unsigned short* __restrict__ outB,
                                                      int M, int N, int K, int sA, int sW) {
  __shared__ unsigned short lds[2][3][128 * 64];  // 96 KB
  int nbn = N >> 7;
  int nwg = gridDim.x;
  int bid = blockIdx.x;
  int wg = (bid & 7) * (nwg >> 3) + (bid >> 3);  // XCD swizzle (nwg % 8 == 0)
  int tm = wg / nbn, tn = wg % nbn;
  int tid = threadIdx.x;
  int wave = tid >> 6, lane = tid & 63;
  int wr = wave >> 2, wc = wave & 3;  // per-wave C = 128 rows x 32 cols
  int l15 = lane & 15, g = lane >> 4;
  int nt = K >> 6;

  const unsigned short* Abase = A + (size_t)(tm * 256) * sA;
  const unsigned short* Wbase = W + (size_t)(tn * 128) * sW;
  int srow = tid >> 3;
  int schunk = (tid & 7) ^ (srow & 7);

  f32x4 acc[8][2] = {};
  bf16x8 afrA[2][2], afrB[2][2], bfr[2][2];

  auto stage = [&](int buf, int s, int kt) {
    const unsigned short* base = (s < 2) ? Abase : Wbase;
    int str = (s < 2) ? sA : sW;
    int rbase = (s & 1) * 128;  // s=2 -> 0
#pragma unroll
    for (int e = 0; e < 2; ++e) {
      gld16(base + (size_t)(rbase + srow + e * 64) * str + kt * 64 + schunk * 8,
            &lds[buf][s][wave * 512 + e * 4096]);
    }
  };
  auto readB = [&](int buf) {
    const unsigned short* Bh = &lds[buf][2][0];
#pragma unroll
    for (int kk = 0; kk < 2; ++kk)
#pragma unroll
      for (int j = 0; j < 2; ++j) {
        int br = wc * 32 + j * 16 + l15;
        bfr[kk][j] = *(const bf16x8*)&Bh[br * 64 + (((kk * 4 + g) ^ (br & 7)) * 8)];
      }
  };
  auto readA = [&](bf16x8 (&dst)[2][2], int buf, int q) {
    const unsigned short* Ah = &lds[buf][wr][0];
#pragma unroll
    for (int kk = 0; kk < 2; ++kk)
#pragma unroll
      for (int ri = 0; ri < 2; ++ri) {
        int ar = q * 32 + ri * 16 + l15;
        dst[kk][ri] = *(const bf16x8*)&Ah[ar * 64 + (((kk * 4 + g) ^ (ar & 7)) * 8)];
      }
  };
  auto mfma8 = [&](bf16x8 (&af)[2][2], int q) {
    __builtin_amdgcn_s_setprio(1);
#pragma unroll
    for (int kk = 0; kk < 2; ++kk)
#pragma unroll
      for (int ri = 0; ri < 2; ++ri)
#pragma unroll
        for (int j = 0; j < 2; ++j)
          acc[q * 2 + ri][j] = __builtin_amdgcn_mfma_f32_16x16x32_bf16(
              af[kk][ri], bfr[kk][j], acc[q * 2 + ri][j], 0, 0, 0);
    __builtin_amdgcn_s_setprio(0);
  };

  stage(0, 2, 0); stage(0, 0, 0); stage(0, 1, 0);
  stage(1, 2, 1);
  asm volatile("s_waitcnt vmcnt(2)" ::: "memory");
  __builtin_amdgcn_s_barrier();

  for (int t = 0; t < nt; ++t) {
    int buf = t & 1;
    // phase 0
    __builtin_amdgcn_sched_barrier(0);
    if (t + 1 < nt) stage(buf ^ 1, 0, t + 1);
    readB(buf);
    readA(afrA, buf, 0);
    readA(afrB, buf, 1);
    mfma8(afrA, 0);
    __builtin_amdgcn_s_barrier();
    // phase 1
    __builtin_amdgcn_sched_barrier(0);
    if (t + 1 < nt) stage(buf ^ 1, 1, t + 1);
    readA(afrA, buf, 2);
    mfma8(afrB, 1);
    __builtin_amdgcn_s_barrier();
    // phase 2
    __builtin_amdgcn_sched_barrier(0);
    if (t + 2 < nt) stage(buf, 2, t + 2);
    readA(afrB, buf, 3);
    mfma8(afrA, 2);
    __builtin_amdgcn_s_barrier();
    // phase 3: no ds_reads
    __builtin_amdgcn_sched_barrier(0);
    mfma8(afrB, 3);
    if (t + 2 < nt) asm volatile("s_waitcnt vmcnt(2)" ::: "memory");
    else asm volatile("s_waitcnt vmcnt(0)" ::: "memory");
    __builtin_amdgcn_s_barrier();
  }

  int row0 = tm * 256 + wr * 128 + g * 4;
  int col0 = tn * 128 + wc * 32 + l15;
#pragma unroll
  for (int i = 0; i < 8; ++i) {
#pragma unroll
    for (int j = 0; j < 2; ++j) {
      int col = col0 + j * 16;
      float cb = (MODE == 2) ? bias[col] : 0.0f;
#pragma unroll
      for (int r = 0; r < 4; ++r) {
        int row = row0 + i * 16 + r;
        size_t idx = (size_t)row * N + col;
        float v = acc[i][j][r];
        if (MODE == 1) outB[idx] = f2b(v + bias[row]);
        else if (MODE == 2) outF[idx] = resid[idx] + v + cb;
        else outF[idx] += v;
      }
    }
  }
}

// ---------- flash attention v11: v9 (8 waves x 2 q-sets) + 128-key super-tiles ----------
// QK [tok][2048] bf16 (Q cols 0-1023, K cols 1024-2047), Vt [h*64+d][tok] bf16.
// 1 block = (b,h,256-row q-tile); 8 waves; wave owns q rows q0+wave*16+l15 (set A)
// and q0+128+wave*16+l15 (set B). Super-tile = 128 keys (2 sub-tiles): ONE barrier
// per 2 kt (8 total), doubled prefetch distance; mask-bias loads hoisted and
// shared across both q-sets. LDS 68KB -> 2 blocks/CU. grid 512.
__global__ __launch_bounds__(512, 4) void attn_fwd11(const unsigned short* __restrict__ QK,
                                                     const unsigned short* __restrict__ Vt,
                                                     const int* __restrict__ mask,
                                                     unsigned short* __restrict__ O) {
  __shared__ unsigned short Kl[2][2][64 * 64];
  __shared__ unsigned short Vl[2][2][64 * 64];
  __shared__ float biasl[1024];
  int bid = blockIdx.x;
  int wg = (bid & 7) * 64 + (bid >> 3);  // XCD swizzle (nwg = 512)
  int qt = wg & 3, bh = wg >> 2;
  int b = bh >> 4, h = bh & 15;
  int tid = threadIdx.x, wave = tid >> 6, lane = tid & 63;
  int l15 = lane & 15, g = lane >> 4;
  int q0 = qt * 256;

  for (int i = tid; i < 1024; i += 512)
    biasl[i] = (mask[b * 1024 + i] == 0) ? -1.4426950e9f : 0.0f;

  const unsigned short* QrowA = QK + ((size_t)(b * 1024 + q0 + wave * 16 + l15)) * 2048 + h * 64;
  const unsigned short* QrowB = QrowA + (size_t)128 * 2048;
  bf16x8 qa0 = *(const bf16x8*)(QrowA + g * 8);
  bf16x8 qa1 = *(const bf16x8*)(QrowA + 32 + g * 8);
  bf16x8 qb0 = *(const bf16x8*)(QrowB + g * 8);
  bf16x8 qb1 = *(const bf16x8*)(QrowB + 32 + g * 8);

  float l_a = 0.0f, l_b = 0.0f;   // lane-partial softmax denominators
  f32x4 oa[4] = {}, ob[4] = {};   // o[dt][r] = O[q][d = dt*16 + g*4 + r]

  int srow = tid >> 3;                // 0..63: staged row
  int clog = (tid & 7) ^ (srow & 7);  // inverse-swizzled chunk
  int h7 = l15 & 7;
  const float SC = 0.125f * 1.44269504f;  // 1/sqrt(64) * log2(e)

  auto stageKV = [&](int buf, int st) {
#pragma unroll
    for (int s = 0; s < 2; ++s) {
      int key0 = st * 128 + s * 64;
      gld16(QK + ((size_t)(b * 1024 + key0 + srow)) * 2048 + 1024 + h * 64 + clog * 8,
            &Kl[buf][s][(wave * 8) * 64]);
      gld16(Vt + ((size_t)(h * 64 + srow)) * 8192 + b * 1024 + key0 + clog * 8,
            &Vl[buf][s][(wave * 8) * 64]);
    }
  };

  stageKV(0, 0);
  __syncthreads();

  union U8 { uint32_t u[4]; bf16x8 v; };

  for (int st = 0; st < 8; ++st) {
    int buf = st & 1;
    if (st < 7) stageKV(buf ^ 1, st + 1);  // prefetch next super-tile (2 kt ahead)

#pragma unroll
    for (int s = 0; s < 2; ++s) {
      int kt = st * 2 + s;
      const unsigned short* Kb_ = &Kl[buf][s][0];
      const unsigned short* Vb_ = &Vl[buf][s][0];

      // mask-bias loads hoisted, shared by both q-sets (keys identical)
      float4 b4[4];
#pragma unroll
      for (int j = 0; j < 4; ++j) b4[j] = *(const float4*)&biasl[kt * 64 + j * 16 + g * 4];

      // S^T = mfma(A=K, B=Q): one K-frag pair feeds both q-sets
      f32x4 sa[4], sb[4];
      __builtin_amdgcn_s_setprio(1);
#pragma unroll
      for (int j = 0; j < 4; ++j) {
        int kr = j * 16 + l15;
        bf16x8 ka = *(const bf16x8*)&Kb_[kr * 64 + ((g ^ h7) * 8)];
        bf16x8 kb = *(const bf16x8*)&Kb_[kr * 64 + (((4 + g) ^ h7) * 8)];
        f32x4 z = {};
        sa[j] = __builtin_amdgcn_mfma_f32_16x16x32_bf16(ka, qa0, z, 0, 0, 0);
        sa[j] = __builtin_amdgcn_mfma_f32_16x16x32_bf16(kb, qa1, sa[j], 0, 0, 0);
        sb[j] = __builtin_amdgcn_mfma_f32_16x16x32_bf16(ka, qb0, z, 0, 0, 0);
        sb[j] = __builtin_amdgcn_mfma_f32_16x16x32_bf16(kb, qb1, sb[j], 0, 0, 0);
      }
      __builtin_amdgcn_s_setprio(0);

      // P = exp2(score*SC + maskbias), lane-partial l; pack both sets
      U8 pa[2], pb[2];
#pragma unroll
      for (int j = 0; j < 4; ++j) {
        float ea0 = exp2_fast(sa[j][0] * SC + b4[j].x);
        float ea1 = exp2_fast(sa[j][1] * SC + b4[j].y);
        float ea2 = exp2_fast(sa[j][2] * SC + b4[j].z);
        float ea3 = exp2_fast(sa[j][3] * SC + b4[j].w);
        l_a += (ea0 + ea1) + (ea2 + ea3);
        pa[j >> 1].u[(j & 1) * 2 + 0] = cvtpk(ea0, ea1);
        pa[j >> 1].u[(j & 1) * 2 + 1] = cvtpk(ea2, ea3);
        float eb0 = exp2_fast(sb[j][0] * SC + b4[j].x);
        float eb1 = exp2_fast(sb[j][1] * SC + b4[j].y);
        float eb2 = exp2_fast(sb[j][2] * SC + b4[j].z);
        float eb3 = exp2_fast(sb[j][3] * SC + b4[j].w);
        l_b += (eb0 + eb1) + (eb2 + eb3);
        pb[j >> 1].u[(j & 1) * 2 + 0] = cvtpk(eb0, eb1);
        pb[j >> 1].u[(j & 1) * 2 + 1] = cvtpk(eb2, eb3);
      }

      // PV: one V-frag feeds both q-sets
      __builtin_amdgcn_s_setprio(1);
#pragma unroll
      for (int kk = 0; kk < 2; ++kk) {
#pragma unroll
        for (int dt = 0; dt < 4; ++dt) {
          int vr = dt * 16 + l15;
          uint2 lo = *(const uint2*)&Vb_[vr * 64 + (((4 * kk + (g >> 1)) ^ h7) * 8) + (g & 1) * 4];
          uint2 hi = *(const uint2*)&Vb_[vr * 64 + (((4 * kk + 2 + (g >> 1)) ^ h7) * 8) + (g & 1) * 4];
          U8 vbu;
          vbu.u[0] = lo.x; vbu.u[1] = lo.y; vbu.u[2] = hi.x; vbu.u[3] = hi.y;
          oa[dt] = __builtin_amdgcn_mfma_f32_16x16x32_bf16(vbu.v, pa[kk].v, oa[dt], 0, 0, 0);
          ob[dt] = __builtin_amdgcn_mfma_f32_16x16x32_bf16(vbu.v, pb[kk].v, ob[dt], 0, 0, 0);
        }
      }
      __builtin_amdgcn_s_setprio(0);
    }

    __syncthreads();  // one barrier per super-tile: reads of buf done + next loads landed
  }

  // final l reduce across the 4 lane-copies of each q, then lane-local epilogue
  l_a += __shfl_xor(l_a, 16);
  l_a += __shfl_xor(l_a, 32);
  l_b += __shfl_xor(l_b, 16);
  l_b += __shfl_xor(l_b, 32);
  float inva = 1.0f / l_a, invb = 1.0f / l_b;
  size_t orowA = ((size_t)(b * 1024 + q0 + wave * 16 + l15)) * 1024 + h * 64;
  size_t orowB = orowA + (size_t)128 * 1024;
#pragma unroll
  for (int dt = 0; dt < 4; ++dt) {
    uint2 wa, wb;
    wa.x = cvtpk(oa[dt][0] * inva, oa[dt][1] * inva);
    wa.y = cvtpk(oa[dt][2] * inva, oa[dt][3] * inva);
    *(uint2*)&O[orowA + dt * 16 + g * 4] = wa;
    wb.x = cvtpk(ob[dt][0] * invb, ob[dt][1] * invb);
    wb.y = cvtpk(ob[dt][2] * invb, ob[dt][3] * invb);
    *(uint2*)&O[orowB + dt * 16 + g * 4] = wb;
  }
}

// ---------- launch ----------
extern "C" void kernel_launch(void* const* d_in, const int* in_sizes, int n_in,
                              void* d_out, int out_size, void* d_ws, size_t ws_size,
                              hipStream_t stream) {
  const float* X = (const float*)d_in[0];
  const int* mask = (const int*)d_in[1];
  const float* wq = (const float*)d_in[2];
  const float* bq = (const float*)d_in[3];
  const float* wk = (const float*)d_in[4];
  const float* bk = (const float*)d_in[5];
  const float* wv = (const float*)d_in[6];
  const float* bv = (const float*)d_in[7];
  const float* wo = (const float*)d_in[8];
  const float* bo = (const float*)d_in[9];
  const float* w1 = (const float*)d_in[10];
  const float* b1 = (const float*)d_in[11];
  const float* w2 = (const float*)d_in[12];
  const float* b2 = (const float*)d_in[13];
  const float* ln1a = (const float*)d_in[14];
  const float* ln1b = (const float*)d_in[15];
  const float* ln2a = (const float*)d_in[16];
  const float* ln2b = (const float*)d_in[17];
  float* out = (float*)d_out;
  char* ws = (char*)d_ws;
  const size_t MB = 1024 * 1024;

  // layout (88MB): [0,8) w1_b | [8,16) w2_b | [16,20) wqk_b | [20,22) wv_b |
  // [22,24) wo_b | [24,40) xn (LN1 out -> attn O -> LN2 out) | [40,72) QKb -> hb |
  // [72,88) Vtb
  unsigned short* w1_b = (unsigned short*)(ws + 0 * MB);
  unsigned short* w2_b = (unsigned short*)(ws + 8 * MB);
  unsigned short* wqk_b = (unsigned short*)(ws + 16 * MB);
  unsigned short* wv_b = (unsigned short*)(ws + 20 * MB);
  unsigned short* wo_b = (unsigned short*)(ws + 22 * MB);
  unsigned short* xn = (unsigned short*)(ws + 24 * MB);
  unsigned short* QKb = (unsigned short*)(ws + 40 * MB);
  unsigned short* Vtb = (unsigned short*)(ws + 72 * MB);
  unsigned short* hb = QKb;

  // all weights -> bf16 in one launch (wq,wk stacked into wqk_b)
  cast_all<<<12288, 256, 0, stream>>>(w1, w2, wq, wk, wv, wo, w1_b, w2_b, wqk_b, wv_b, wo_b);

  // LN1
  ln_bf16<<<8192, 256, 0, stream>>>(X, xn, ln1a, ln1b);
  // fused Q+K projection: QK[token][2048]  (256^2 tile, grid 256 = 1/CU)
  gemm256<0, 1><<<256, 512, 0, stream>>>(xn, wqk_b, bq, bk, 1024, QKb,
                                         8192, 2048, 1024, 1024, 1024);
  // V transposed: Vt[hd][token] = wv @ xn^T + bv (row bias)  (256x128, grid 256)
  gemm256x128<1><<<256, 512, 0, stream>>>(wv_b, xn, bv, nullptr, nullptr, Vtb,
                                          1024, 8192, 1024, 1024, 1024);
  // attention (writes O into xn buffer); 512 blocks x 512 thr = 2 blocks/CU
  attn_fwd11<<<512, 512, 0, stream>>>(QKb, Vtb, mask, xn);
  // out = X + O @ wo^T + bo  (256x128, grid 256)
  gemm256x128<2><<<256, 512, 0, stream>>>(xn, wo_b, bo, X, out, nullptr,
                                          8192, 1024, 1024, 1024, 1024);
  // LN2 (reads out, writes into xn region)
  ln_bf16<<<8192, 256, 0, stream>>>(out, xn, ln2a, ln2b);
  // FFN chunked along hidden dim: h half = [8192][2048] in hb (QKb region)
  for (int hc = 0; hc < 2; ++hc) {
    // h = relu(xn @ w1[hc*2048:(hc+1)*2048]^T + b1[hc*2048:])  (256^2)
    gemm256<1, 0><<<256, 512, 0, stream>>>(xn, w1_b + (size_t)hc * 2048 * 1024,
                                           b1 + hc * 2048, nullptr, 0, hb,
                                           8192, 2048, 1024, 1024, 1024);
    if (hc == 0)  // out = out + b2 + h_half @ w2[:, 0:2048]^T  (256x128)
      gemm256x128<2><<<256, 512, 0, stream>>>(hb, w2_b, b2, out, out, nullptr,
                                              8192, 1024, 2048, 2048, 4096);
    else          // out += h_half @ w2[:, 2048:4096]^T  (256x128)
      gemm256x128<3><<<256, 512, 0, stream>>>(hb, w2_b + 2048, nullptr, nullptr, out, nullptr,
                                              8192, 1024, 2048, 2048, 4096);
  }
}

// Round 16
// 357.049 us; speedup vs baseline: 1.2206x; 1.2206x over previous
//
#include <hip/hip_runtime.h>
#include <cstdint>
#include <cstddef>

// ---------- types ----------
typedef float f32x4 __attribute__((ext_vector_type(4)));
typedef short bf16x8 __attribute__((ext_vector_type(8)));

typedef __attribute__((address_space(1))) void void_g;
typedef __attribute__((address_space(3))) void void_l;

__device__ __forceinline__ void gld16(const void* g, void* l) {
  // async global->LDS, 16B per lane; LDS dest = wave-uniform base + lane*16
  __builtin_amdgcn_global_load_lds((void_g*)g, (void_l*)l, 16, 0, 0);
}

__device__ __forceinline__ unsigned short f2b(float f) {
  union { float f; uint32_t u; } c; c.f = f;
  uint32_t u = c.u;
  return (unsigned short)((u + 0x7fffu + ((u >> 16) & 1u)) >> 16);  // RNE
}

__device__ __forceinline__ uint32_t cvtpk(float lo, float hi) {
  uint32_t r;
  asm("v_cvt_pk_bf16_f32 %0, %1, %2" : "=v"(r) : "v"(lo), "v"(hi));
  return r;  // low16 = bf16(lo), high16 = bf16(hi)
}

__device__ __forceinline__ float exp2_fast(float x) {
  return __builtin_exp2f(x);  // lowers to v_exp_f32 (2^x) on gfx950
}

// ---------- all weight casts fp32 -> bf16 in one launch ----------
__global__ __launch_bounds__(256) void cast_all(const float* __restrict__ w1,
                                                const float* __restrict__ w2,
                                                const float* __restrict__ wq,
                                                const float* __restrict__ wk,
                                                const float* __restrict__ wv,
                                                const float* __restrict__ wo,
                                                unsigned short* __restrict__ d1,
                                                unsigned short* __restrict__ d2,
                                                unsigned short* __restrict__ dqk,
                                                unsigned short* __restrict__ dv,
                                                unsigned short* __restrict__ dod) {
  int blk = blockIdx.x;
  const float* s;
  unsigned short* d;
  int off;
  if (blk < 4096) { s = w1; d = d1; off = blk; }
  else if (blk < 8192) { s = w2; d = d2; off = blk - 4096; }
  else if (blk < 9216) { s = wq; d = dqk; off = blk - 8192; }
  else if (blk < 10240) { s = wk; d = dqk + (1 << 20); off = blk - 9216; }
  else if (blk < 11264) { s = wv; d = dv; off = blk - 10240; }
  else { s = wo; d = dod; off = blk - 11264; }
  int i = off * 256 + threadIdx.x;
  float4 v = ((const float4*)s)[i];
  ushort4 o;
  o.x = f2b(v.x); o.y = f2b(v.y); o.z = f2b(v.z); o.w = f2b(v.w);
  ((ushort4*)d)[i] = o;
}

// ---------- LayerNorm (unbiased std, scalar alpha/beta) -> bf16 ----------
__global__ __launch_bounds__(256) void ln_bf16(const float* __restrict__ X,
                                               unsigned short* __restrict__ out,
                                               const float* __restrict__ alpha,
                                               const float* __restrict__ beta) {
  int row = blockIdx.x;
  int tid = threadIdx.x;
  float4 v = ((const float4*)(X + (size_t)row * 1024))[tid];
  float s = v.x + v.y + v.z + v.w;
  float q = v.x * v.x + v.y * v.y + v.z * v.z + v.w * v.w;
#pragma unroll
  for (int m = 1; m < 64; m <<= 1) { s += __shfl_xor(s, m); q += __shfl_xor(q, m); }
  __shared__ float red[8];
  int wave = tid >> 6;
  if ((tid & 63) == 0) { red[wave] = s; red[4 + wave] = q; }
  __syncthreads();
  s = red[0] + red[1] + red[2] + red[3];
  q = red[4] + red[5] + red[6] + red[7];
  float mean = s * (1.0f / 1024.0f);
  float var = fmaxf((q - 1024.0f * mean * mean) * (1.0f / 1023.0f), 0.0f);
  float inv = alpha[0] / (sqrtf(var) + 1e-6f);
  float b = beta[0];
  ushort4 o;
  o.x = f2b((v.x - mean) * inv + b);
  o.y = f2b((v.y - mean) * inv + b);
  o.z = f2b((v.z - mean) * inv + b);
  o.w = f2b((v.w - mean) * inv + b);
  ((ushort4*)(out + (size_t)row * 1024))[tid] = o;
}

// ---------- GEMM 256x256 8-wave, BK=64, counted-vmcnt + frag-prefetch pipeline ----------
template <int RELU, int BIAS2>
__global__ __launch_bounds__(512, 1) void gemm256(const unsigned short* __restrict__ A,
                                                  const unsigned short* __restrict__ W,
                                                  const float* __restrict__ bias,
                                                  const float* __restrict__ bias2, int b2off,
                                                  unsigned short* __restrict__ outB,
                                                  int M, int N, int K, int sA, int sW) {
  __shared__ unsigned short lds[2][4][128 * 64];  // 128 KB
  int nbn = N >> 8;
  int nwg = gridDim.x;
  int bid = blockIdx.x;
  int wg = (bid & 7) * (nwg >> 3) + (bid >> 3);  // XCD swizzle (nwg % 8 == 0)
  int tm = wg / nbn, tn = wg % nbn;
  int tid = threadIdx.x;
  int wave = tid >> 6, lane = tid & 63;
  int wr = wave >> 2, wc = wave & 3;  // 2 x 4 wave grid; per-wave C = 128 x 64
  int l15 = lane & 15, g = lane >> 4;
  int nt = K >> 6;

  const unsigned short* Abase = A + (size_t)(tm * 256) * sA;
  const unsigned short* Wbase = W + (size_t)(tn * 256) * sW;
  int srow = tid >> 3;
  int schunk = (tid & 7) ^ (srow & 7);

  f32x4 acc[8][4] = {};
  bf16x8 afrA[2][2], afrB[2][2], bfr[2][4];

  auto stage = [&](int buf, int s, int kt) {
    const unsigned short* base = (s < 2) ? Abase : Wbase;
    int str = (s < 2) ? sA : sW;
    int rbase = (s & 1) * 128;
#pragma unroll
    for (int e = 0; e < 2; ++e) {
      gld16(base + (size_t)(rbase + srow + e * 64) * str + kt * 64 + schunk * 8,
            &lds[buf][s][wave * 512 + e * 4096]);
    }
  };
  auto readB = [&](int buf) {
    const unsigned short* Bh = &lds[buf][2 + (wc >> 1)][0];
#pragma unroll
    for (int kk = 0; kk < 2; ++kk)
#pragma unroll
      for (int j = 0; j < 4; ++j) {
        int br = (wc & 1) * 64 + j * 16 + l15;
        bfr[kk][j] = *(const bf16x8*)&Bh[br * 64 + (((kk * 4 + g) ^ (br & 7)) * 8)];
      }
  };
  auto readA = [&](bf16x8 (&dst)[2][2], int buf, int q) {
    const unsigned short* Ah = &lds[buf][wr][0];
#pragma unroll
    for (int kk = 0; kk < 2; ++kk)
#pragma unroll
      for (int ri = 0; ri < 2; ++ri) {
        int ar = q * 32 + ri * 16 + l15;
        dst[kk][ri] = *(const bf16x8*)&Ah[ar * 64 + (((kk * 4 + g) ^ (ar & 7)) * 8)];
      }
  };
  auto mfma16 = [&](bf16x8 (&af)[2][2], int q) {
    __builtin_amdgcn_s_setprio(1);
#pragma unroll
    for (int kk = 0; kk < 2; ++kk)
#pragma unroll
      for (int ri = 0; ri < 2; ++ri)
#pragma unroll
        for (int j = 0; j < 4; ++j)
          acc[q * 2 + ri][j] = __builtin_amdgcn_mfma_f32_16x16x32_bf16(
              af[kk][ri], bfr[kk][j], acc[q * 2 + ri][j], 0, 0, 0);
    __builtin_amdgcn_s_setprio(0);
  };

  stage(0, 2, 0); stage(0, 3, 0); stage(0, 0, 0); stage(0, 1, 0);
  stage(1, 2, 1); stage(1, 3, 1);
  asm volatile("s_waitcnt vmcnt(4)" ::: "memory");
  __builtin_amdgcn_s_barrier();

  for (int t = 0; t < nt; ++t) {
    int buf = t & 1;
    // phase 0: B frags + afrA(q0) + prefetch afrB(q1)
    __builtin_amdgcn_sched_barrier(0);
    if (t + 1 < nt) stage(buf ^ 1, 0, t + 1);
    readB(buf);
    readA(afrA, buf, 0);
    readA(afrB, buf, 1);
    mfma16(afrA, 0);
    __builtin_amdgcn_s_barrier();
    // phase 1: prefetch afrA(q2)
    __builtin_amdgcn_sched_barrier(0);
    if (t + 1 < nt) stage(buf ^ 1, 1, t + 1);
    readA(afrA, buf, 2);
    mfma16(afrB, 1);
    __builtin_amdgcn_s_barrier();
    // phase 2: prefetch afrB(q3)
    __builtin_amdgcn_sched_barrier(0);
    if (t + 2 < nt) stage(buf, 2, t + 2);
    readA(afrB, buf, 3);
    mfma16(afrA, 2);
    __builtin_amdgcn_s_barrier();
    // phase 3: no ds_reads; MFMA covers vmcnt drain
    __builtin_amdgcn_sched_barrier(0);
    if (t + 2 < nt) stage(buf, 3, t + 2);
    mfma16(afrB, 3);
    if (t + 2 < nt) asm volatile("s_waitcnt vmcnt(4)" ::: "memory");
    else asm volatile("s_waitcnt vmcnt(0)" ::: "memory");
    __builtin_amdgcn_s_barrier();
  }

  int row0 = tm * 256 + wr * 128 + g * 4;
  int col0 = tn * 256 + wc * 64 + l15;
#pragma unroll
  for (int i = 0; i < 8; ++i) {
#pragma unroll
    for (int j = 0; j < 4; ++j) {
      int col = col0 + j * 16;
      float bb = (BIAS2 && col >= b2off) ? bias2[col - b2off] : bias[col];
#pragma unroll
      for (int r = 0; r < 4; ++r) {
        int row = row0 + i * 16 + r;
        float v = acc[i][j][r] + bb;
        if (RELU) v = fmaxf(v, 0.0f);
        outB[(size_t)row * N + col] = f2b(v);
      }
    }
  }
}

// ---------- GEMM 256x128 8-wave, BK=64, counted-vmcnt + frag-prefetch ----------
// MODE: 1 = bf16 out + row bias; 2 = fp32 out = resid + v + col bias; 3 = fp32 out += v.
template <int MODE>
__global__ __launch_bounds__(512, 1) void gemm256x128(const unsigned short* __restrict__ A,
                                                      const unsigned short* __restrict__ W,
                                                      const float* __restrict__ bias,
                                                      const float* __restrict__ resid,
                                                      float* __restrict__ outF,
                                                      unsigned short* __restrict__ outB,
                                                      int M, int N, int K, int sA, int sW) {
  __shared__ unsigned short lds[2][3][128 * 64];  // 96 KB
  int nbn = N >> 7;
  int nwg = gridDim.x;
  int bid = blockIdx.x;
  int wg = (bid & 7) * (nwg >> 3) + (bid >> 3);  // XCD swizzle (nwg % 8 == 0)
  int tm = wg / nbn, tn = wg % nbn;
  int tid = threadIdx.x;
  int wave = tid >> 6, lane = tid & 63;
  int wr = wave >> 2, wc = wave & 3;  // per-wave C = 128 rows x 32 cols
  int l15 = lane & 15, g = lane >> 4;
  int nt = K >> 6;

  const unsigned short* Abase = A + (size_t)(tm * 256) * sA;
  const unsigned short* Wbase = W + (size_t)(tn * 128) * sW;
  int srow = tid >> 3;
  int schunk = (tid & 7) ^ (srow & 7);

  f32x4 acc[8][2] = {};
  bf16x8 afrA[2][2], afrB[2][2], bfr[2][2];

  auto stage = [&](int buf, int s, int kt) {
    const unsigned short* base = (s < 2) ? Abase : Wbase;
    int str = (s < 2) ? sA : sW;
    int rbase = (s & 1) * 128;  // s=2 -> 0
#pragma unroll
    for (int e = 0; e < 2; ++e) {
      gld16(base + (size_t)(rbase + srow + e * 64) * str + kt * 64 + schunk * 8,
            &lds[buf][s][wave * 512 + e * 4096]);
    }
  };
  auto readB = [&](int buf) {
    const unsigned short* Bh = &lds[buf][2][0];
#pragma unroll
    for (int kk = 0; kk < 2; ++kk)
#pragma unroll
      for (int j = 0; j < 2; ++j) {
        int br = wc * 32 + j * 16 + l15;
        bfr[kk][j] = *(const bf16x8*)&Bh[br * 64 + (((kk * 4 + g) ^ (br & 7)) * 8)];
      }
  };
  auto readA = [&](bf16x8 (&dst)[2][2], int buf, int q) {
    const unsigned short* Ah = &lds[buf][wr][0];
#pragma unroll
    for (int kk = 0; kk < 2; ++kk)
#pragma unroll
      for (int ri = 0; ri < 2; ++ri) {
        int ar = q * 32 + ri * 16 + l15;
        dst[kk][ri] = *(const bf16x8*)&Ah[ar * 64 + (((kk * 4 + g) ^ (ar & 7)) * 8)];
      }
  };
  auto mfma8 = [&](bf16x8 (&af)[2][2], int q) {
    __builtin_amdgcn_s_setprio(1);
#pragma unroll
    for (int kk = 0; kk < 2; ++kk)
#pragma unroll
      for (int ri = 0; ri < 2; ++ri)
#pragma unroll
        for (int j = 0; j < 2; ++j)
          acc[q * 2 + ri][j] = __builtin_amdgcn_mfma_f32_16x16x32_bf16(
              af[kk][ri], bfr[kk][j], acc[q * 2 + ri][j], 0, 0, 0);
    __builtin_amdgcn_s_setprio(0);
  };

  stage(0, 2, 0); stage(0, 0, 0); stage(0, 1, 0);
  stage(1, 2, 1);
  asm volatile("s_waitcnt vmcnt(2)" ::: "memory");
  __builtin_amdgcn_s_barrier();

  for (int t = 0; t < nt; ++t) {
    int buf = t & 1;
    // phase 0
    __builtin_amdgcn_sched_barrier(0);
    if (t + 1 < nt) stage(buf ^ 1, 0, t + 1);
    readB(buf);
    readA(afrA, buf, 0);
    readA(afrB, buf, 1);
    mfma8(afrA, 0);
    __builtin_amdgcn_s_barrier();
    // phase 1
    __builtin_amdgcn_sched_barrier(0);
    if (t + 1 < nt) stage(buf ^ 1, 1, t + 1);
    readA(afrA, buf, 2);
    mfma8(afrB, 1);
    __builtin_amdgcn_s_barrier();
    // phase 2
    __builtin_amdgcn_sched_barrier(0);
    if (t + 2 < nt) stage(buf, 2, t + 2);
    readA(afrB, buf, 3);
    mfma8(afrA, 2);
    __builtin_amdgcn_s_barrier();
    // phase 3: no ds_reads
    __builtin_amdgcn_sched_barrier(0);
    mfma8(afrB, 3);
    if (t + 2 < nt) asm volatile("s_waitcnt vmcnt(2)" ::: "memory");
    else asm volatile("s_waitcnt vmcnt(0)" ::: "memory");
    __builtin_amdgcn_s_barrier();
  }

  int row0 = tm * 256 + wr * 128 + g * 4;
  int col0 = tn * 128 + wc * 32 + l15;
#pragma unroll
  for (int i = 0; i < 8; ++i) {
#pragma unroll
    for (int j = 0; j < 2; ++j) {
      int col = col0 + j * 16;
      float cb = (MODE == 2) ? bias[col] : 0.0f;
#pragma unroll
      for (int r = 0; r < 4; ++r) {
        int row = row0 + i * 16 + r;
        size_t idx = (size_t)row * N + col;
        float v = acc[i][j][r];
        if (MODE == 1) outB[idx] = f2b(v + bias[row]);
        else if (MODE == 2) outF[idx] = resid[idx] + v + cb;
        else outF[idx] += v;
      }
    }
  }
}

// ---------- flash attention v9b: 8 waves x 2 q-sets (256 q-rows/block), bias hoisted ----------
// Proven v9 structure (R13: 68us): 64-key tiles, plain __syncthreads pipeline,
// one K/V LDS read feeds both q-sets. Only change: mask-bias float4 loads hoisted
// once per kt and shared by both q-sets (-4 ds_read_b128/wave/kt).
__global__ __launch_bounds__(512, 4) void attn_fwd9(const unsigned short* __restrict__ QK,
                                                    const unsigned short* __restrict__ Vt,
                                                    const int* __restrict__ mask,
                                                    unsigned short* __restrict__ O) {
  __shared__ unsigned short Kl[2][64 * 64];
  __shared__ unsigned short Vl[2][64 * 64];
  __shared__ float biasl[1024];
  int bid = blockIdx.x;
  int wg = (bid & 7) * 64 + (bid >> 3);  // XCD swizzle (nwg = 512)
  int qt = wg & 3, bh = wg >> 2;
  int b = bh >> 4, h = bh & 15;
  int tid = threadIdx.x, wave = tid >> 6, lane = tid & 63;
  int l15 = lane & 15, g = lane >> 4;
  int q0 = qt * 256;

  for (int i = tid; i < 1024; i += 512)
    biasl[i] = (mask[b * 1024 + i] == 0) ? -1.4426950e9f : 0.0f;

  const unsigned short* QrowA = QK + ((size_t)(b * 1024 + q0 + wave * 16 + l15)) * 2048 + h * 64;
  const unsigned short* QrowB = QrowA + (size_t)128 * 2048;
  bf16x8 qa0 = *(const bf16x8*)(QrowA + g * 8);
  bf16x8 qa1 = *(const bf16x8*)(QrowA + 32 + g * 8);
  bf16x8 qb0 = *(const bf16x8*)(QrowB + g * 8);
  bf16x8 qb1 = *(const bf16x8*)(QrowB + 32 + g * 8);

  float l_a = 0.0f, l_b = 0.0f;   // lane-partial softmax denominators
  f32x4 oa[4] = {}, ob[4] = {};   // o[dt][r] = O[q][d = dt*16 + g*4 + r]

  int srow = tid >> 3;                // 0..63: staged row
  int clog = (tid & 7) ^ (srow & 7);  // inverse-swizzled chunk
  int h7 = l15 & 7;
  const float SC = 0.125f * 1.44269504f;  // 1/sqrt(64) * log2(e)

  auto stageKV = [&](int buf, int kt) {
    gld16(QK + ((size_t)(b * 1024 + kt * 64 + srow)) * 2048 + 1024 + h * 64 + clog * 8,
          &Kl[buf][(wave * 8) * 64]);
    gld16(Vt + ((size_t)(h * 64 + srow)) * 8192 + b * 1024 + kt * 64 + clog * 8,
          &Vl[buf][(wave * 8) * 64]);
  };

  stageKV(0, 0);
  __syncthreads();
  int cur = 0;

  for (int kt = 0; kt < 16; ++kt) {
    if (kt < 15) stageKV(cur ^ 1, kt + 1);

    // hoisted mask-bias loads (shared by both q-sets; keys identical)
    float4 b4[4];
#pragma unroll
    for (int j = 0; j < 4; ++j) b4[j] = *(const float4*)&biasl[kt * 64 + j * 16 + g * 4];

    // S^T = mfma(A=K, B=Q): one K-frag pair feeds both q-sets
    f32x4 sa[4], sb[4];
    __builtin_amdgcn_s_setprio(1);
#pragma unroll
    for (int j = 0; j < 4; ++j) {
      int kr = j * 16 + l15;
      bf16x8 ka = *(const bf16x8*)&Kl[cur][kr * 64 + ((g ^ h7) * 8)];
      bf16x8 kb = *(const bf16x8*)&Kl[cur][kr * 64 + (((4 + g) ^ h7) * 8)];
      f32x4 z = {};
      sa[j] = __builtin_amdgcn_mfma_f32_16x16x32_bf16(ka, qa0, z, 0, 0, 0);
      sa[j] = __builtin_amdgcn_mfma_f32_16x16x32_bf16(kb, qa1, sa[j], 0, 0, 0);
      sb[j] = __builtin_amdgcn_mfma_f32_16x16x32_bf16(ka, qb0, z, 0, 0, 0);
      sb[j] = __builtin_amdgcn_mfma_f32_16x16x32_bf16(kb, qb1, sb[j], 0, 0, 0);
    }
    __builtin_amdgcn_s_setprio(0);

    // P = exp2(score*SC + maskbias), lane-partial l; pack both sets
    union U8 { uint32_t u[4]; bf16x8 v; } pa[2], pb[2];
#pragma unroll
    for (int j = 0; j < 4; ++j) {
      float ea0 = exp2_fast(sa[j][0] * SC + b4[j].x);
      float ea1 = exp2_fast(sa[j][1] * SC + b4[j].y);
      float ea2 = exp2_fast(sa[j][2] * SC + b4[j].z);
      float ea3 = exp2_fast(sa[j][3] * SC + b4[j].w);
      l_a += (ea0 + ea1) + (ea2 + ea3);
      pa[j >> 1].u[(j & 1) * 2 + 0] = cvtpk(ea0, ea1);
      pa[j >> 1].u[(j & 1) * 2 + 1] = cvtpk(ea2, ea3);
      float eb0 = exp2_fast(sb[j][0] * SC + b4[j].x);
      float eb1 = exp2_fast(sb[j][1] * SC + b4[j].y);
      float eb2 = exp2_fast(sb[j][2] * SC + b4[j].z);
      float eb3 = exp2_fast(sb[j][3] * SC + b4[j].w);
      l_b += (eb0 + eb1) + (eb2 + eb3);
      pb[j >> 1].u[(j & 1) * 2 + 0] = cvtpk(eb0, eb1);
      pb[j >> 1].u[(j & 1) * 2 + 1] = cvtpk(eb2, eb3);
    }

    // PV: one V-frag feeds both q-sets
    __builtin_amdgcn_s_setprio(1);
#pragma unroll
    for (int kk = 0; kk < 2; ++kk) {
#pragma unroll
      for (int dt = 0; dt < 4; ++dt) {
        int vr = dt * 16 + l15;
        uint2 lo = *(const uint2*)&Vl[cur][vr * 64 + (((4 * kk + (g >> 1)) ^ h7) * 8) + (g & 1) * 4];
        uint2 hi = *(const uint2*)&Vl[cur][vr * 64 + (((4 * kk + 2 + (g >> 1)) ^ h7) * 8) + (g & 1) * 4];
        U8 vbu;
        vbu.u[0] = lo.x; vbu.u[1] = lo.y; vbu.u[2] = hi.x; vbu.u[3] = hi.y;
        oa[dt] = __builtin_amdgcn_mfma_f32_16x16x32_bf16(vbu.v, pa[kk].v, oa[dt], 0, 0, 0);
        ob[dt] = __builtin_amdgcn_mfma_f32_16x16x32_bf16(vbu.v, pb[kk].v, ob[dt], 0, 0, 0);
      }
    }
    __builtin_amdgcn_s_setprio(0);

    __syncthreads();
    cur ^= 1;
  }

  // final l reduce across the 4 lane-copies of each q, then lane-local epilogue
  l_a += __shfl_xor(l_a, 16);
  l_a += __shfl_xor(l_a, 32);
  l_b += __shfl_xor(l_b, 16);
  l_b += __shfl_xor(l_b, 32);
  float inva = 1.0f / l_a, invb = 1.0f / l_b;
  size_t orowA = ((size_t)(b * 1024 + q0 + wave * 16 + l15)) * 1024 + h * 64;
  size_t orowB = orowA + (size_t)128 * 1024;
#pragma unroll
  for (int dt = 0; dt < 4; ++dt) {
    uint2 wa, wb;
    wa.x = cvtpk(oa[dt][0] * inva, oa[dt][1] * inva);
    wa.y = cvtpk(oa[dt][2] * inva, oa[dt][3] * inva);
    *(uint2*)&O[orowA + dt * 16 + g * 4] = wa;
    wb.x = cvtpk(ob[dt][0] * invb, ob[dt][1] * invb);
    wb.y = cvtpk(ob[dt][2] * invb, ob[dt][3] * invb);
    *(uint2*)&O[orowB + dt * 16 + g * 4] = wb;
  }
}

// ---------- launch ----------
extern "C" void kernel_launch(void* const* d_in, const int* in_sizes, int n_in,
                              void* d_out, int out_size, void* d_ws, size_t ws_size,
                              hipStream_t stream) {
  const float* X = (const float*)d_in[0];
  const int* mask = (const int*)d_in[1];
  const float* wq = (const float*)d_in[2];
  const float* bq = (const float*)d_in[3];
  const float* wk = (const float*)d_in[4];
  const float* bk = (const float*)d_in[5];
  const float* wv = (const float*)d_in[6];
  const float* bv = (const float*)d_in[7];
  const float* wo = (const float*)d_in[8];
  const float* bo = (const float*)d_in[9];
  const float* w1 = (const float*)d_in[10];
  const float* b1 = (const float*)d_in[11];
  const float* w2 = (const float*)d_in[12];
  const float* b2 = (const float*)d_in[13];
  const float* ln1a = (const float*)d_in[14];
  const float* ln1b = (const float*)d_in[15];
  const float* ln2a = (const float*)d_in[16];
  const float* ln2b = (const float*)d_in[17];
  float* out = (float*)d_out;
  char* ws = (char*)d_ws;
  const size_t MB = 1024 * 1024;

  // layout (88MB): [0,8) w1_b | [8,16) w2_b | [16,20) wqk_b | [20,22) wv_b |
  // [22,24) wo_b | [24,40) xn (LN1 out -> attn O -> LN2 out) | [40,72) QKb -> hb |
  // [72,88) Vtb
  unsigned short* w1_b = (unsigned short*)(ws + 0 * MB);
  unsigned short* w2_b = (unsigned short*)(ws + 8 * MB);
  unsigned short* wqk_b = (unsigned short*)(ws + 16 * MB);
  unsigned short* wv_b = (unsigned short*)(ws + 20 * MB);
  unsigned short* wo_b = (unsigned short*)(ws + 22 * MB);
  unsigned short* xn = (unsigned short*)(ws + 24 * MB);
  unsigned short* QKb = (unsigned short*)(ws + 40 * MB);
  unsigned short* Vtb = (unsigned short*)(ws + 72 * MB);
  unsigned short* hb = QKb;

  // all weights -> bf16 in one launch (wq,wk stacked into wqk_b)
  cast_all<<<12288, 256, 0, stream>>>(w1, w2, wq, wk, wv, wo, w1_b, w2_b, wqk_b, wv_b, wo_b);

  // LN1
  ln_bf16<<<8192, 256, 0, stream>>>(X, xn, ln1a, ln1b);
  // fused Q+K projection: QK[token][2048]  (256^2 tile, grid 256 = 1/CU)
  gemm256<0, 1><<<256, 512, 0, stream>>>(xn, wqk_b, bq, bk, 1024, QKb,
                                         8192, 2048, 1024, 1024, 1024);
  // V transposed: Vt[hd][token] = wv @ xn^T + bv (row bias)  (256x128, grid 256)
  gemm256x128<1><<<256, 512, 0, stream>>>(wv_b, xn, bv, nullptr, nullptr, Vtb,
                                          1024, 8192, 1024, 1024, 1024);
  // attention (writes O into xn buffer); 512 blocks x 512 thr = 2 blocks/CU
  attn_fwd9<<<512, 512, 0, stream>>>(QKb, Vtb, mask, xn);
  // out = X + O @ wo^T + bo  (256x128, grid 256)
  gemm256x128<2><<<256, 512, 0, stream>>>(xn, wo_b, bo, X, out, nullptr,
                                          8192, 1024, 1024, 1024, 1024);
  // LN2 (reads out, writes into xn region)
  ln_bf16<<<8192, 256, 0, stream>>>(out, xn, ln2a, ln2b);
  // FFN chunked along hidden dim: h half = [8192][2048] in hb (QKb region)
  for (int hc = 0; hc < 2; ++hc) {
    // h = relu(xn @ w1[hc*2048:(hc+1)*2048]^T + b1[hc*2048:])  (256^2)
    gemm256<1, 0><<<256, 512, 0, stream>>>(xn, w1_b + (size_t)hc * 2048 * 1024,
                                           b1 + hc * 2048, nullptr, 0, hb,
                                           8192, 2048, 1024, 1024, 1024);
    if (hc == 0)  // out = out + b2 + h_half @ w2[:, 0:2048]^T  (256x128)
      gemm256x128<2><<<256, 512, 0, stream>>>(hb, w2_b, b2, out, out, nullptr,
                                              8192, 1024, 2048, 2048, 4096);
    else          // out += h_half @ w2[:, 2048:4096]^T  (256x128)
      gemm256x128<3><<<256, 512, 0, stream>>>(hb, w2_b + 2048, nullptr, nullptr, out, nullptr,
                                              8192, 1024, 2048, 2048, 4096);
  }
}

// Round 17
// 345.677 us; speedup vs baseline: 1.2608x; 1.0329x over previous
//
#include <hip/hip_runtime.h>
#include <cstdint>
#include <cstddef>

// ---------- types ----------
typedef float f32x4 __attribute__((ext_vector_type(4)));
typedef short bf16x8 __attribute__((ext_vector_type(8)));

typedef __attribute__((address_space(1))) void void_g;
typedef __attribute__((address_space(3))) void void_l;

__device__ __forceinline__ void gld16(const void* g, void* l) {
  // async global->LDS, 16B per lane; LDS dest = wave-uniform base + lane*16
  __builtin_amdgcn_global_load_lds((void_g*)g, (void_l*)l, 16, 0, 0);
}

__device__ __forceinline__ unsigned short f2b(float f) {
  union { float f; uint32_t u; } c; c.f = f;
  uint32_t u = c.u;
  return (unsigned short)((u + 0x7fffu + ((u >> 16) & 1u)) >> 16);  // RNE
}

__device__ __forceinline__ uint32_t cvtpk(float lo, float hi) {
  uint32_t r;
  asm("v_cvt_pk_bf16_f32 %0, %1, %2" : "=v"(r) : "v"(lo), "v"(hi));
  return r;  // low16 = bf16(lo), high16 = bf16(hi)
}

__device__ __forceinline__ float exp2_fast(float x) {
  return __builtin_exp2f(x);  // lowers to v_exp_f32 (2^x) on gfx950
}

// ---------- all weight casts fp32 -> bf16 in one launch ----------
__global__ __launch_bounds__(256) void cast_all(const float* __restrict__ w1,
                                                const float* __restrict__ w2,
                                                const float* __restrict__ wq,
                                                const float* __restrict__ wk,
                                                const float* __restrict__ wv,
                                                const float* __restrict__ wo,
                                                unsigned short* __restrict__ d1,
                                                unsigned short* __restrict__ d2,
                                                unsigned short* __restrict__ dqk,
                                                unsigned short* __restrict__ dv,
                                                unsigned short* __restrict__ dod) {
  int blk = blockIdx.x;
  const float* s;
  unsigned short* d;
  int off;
  if (blk < 4096) { s = w1; d = d1; off = blk; }
  else if (blk < 8192) { s = w2; d = d2; off = blk - 4096; }
  else if (blk < 9216) { s = wq; d = dqk; off = blk - 8192; }
  else if (blk < 10240) { s = wk; d = dqk + (1 << 20); off = blk - 9216; }
  else if (blk < 11264) { s = wv; d = dv; off = blk - 10240; }
  else { s = wo; d = dod; off = blk - 11264; }
  int i = off * 256 + threadIdx.x;
  float4 v = ((const float4*)s)[i];
  ushort4 o;
  o.x = f2b(v.x); o.y = f2b(v.y); o.z = f2b(v.z); o.w = f2b(v.w);
  ((ushort4*)d)[i] = o;
}

// ---------- LayerNorm (unbiased std, scalar alpha/beta) -> bf16 ----------
__global__ __launch_bounds__(256) void ln_bf16(const float* __restrict__ X,
                                               unsigned short* __restrict__ out,
                                               const float* __restrict__ alpha,
                                               const float* __restrict__ beta) {
  int row = blockIdx.x;
  int tid = threadIdx.x;
  float4 v = ((const float4*)(X + (size_t)row * 1024))[tid];
  float s = v.x + v.y + v.z + v.w;
  float q = v.x * v.x + v.y * v.y + v.z * v.z + v.w * v.w;
#pragma unroll
  for (int m = 1; m < 64; m <<= 1) { s += __shfl_xor(s, m); q += __shfl_xor(q, m); }
  __shared__ float red[8];
  int wave = tid >> 6;
  if ((tid & 63) == 0) { red[wave] = s; red[4 + wave] = q; }
  __syncthreads();
  s = red[0] + red[1] + red[2] + red[3];
  q = red[4] + red[5] + red[6] + red[7];
  float mean = s * (1.0f / 1024.0f);
  float var = fmaxf((q - 1024.0f * mean * mean) * (1.0f / 1023.0f), 0.0f);
  float inv = alpha[0] / (sqrtf(var) + 1e-6f);
  float b = beta[0];
  ushort4 o;
  o.x = f2b((v.x - mean) * inv + b);
  o.y = f2b((v.y - mean) * inv + b);
  o.z = f2b((v.z - mean) * inv + b);
  o.w = f2b((v.w - mean) * inv + b);
  ((ushort4*)(out + (size_t)row * 1024))[tid] = o;
}

// ---------- GEMM 256x256 8-wave, BK=64, counted-vmcnt + frag-prefetch pipeline ----------
// 2 barriers per K-tile (hazard-audited): barrier after phase 1 fences readB/readA
// of slots overwritten by phase-2/3 stages; barrier after phase 3 (with counted
// vmcnt) completes the tile swap. Barriers after phases 0 and 2 removed (dead).
template <int RELU, int BIAS2>
__global__ __launch_bounds__(512, 1) void gemm256(const unsigned short* __restrict__ A,
                                                  const unsigned short* __restrict__ W,
                                                  const float* __restrict__ bias,
                                                  const float* __restrict__ bias2, int b2off,
                                                  unsigned short* __restrict__ outB,
                                                  int M, int N, int K, int sA, int sW) {
  __shared__ unsigned short lds[2][4][128 * 64];  // 128 KB
  int nbn = N >> 8;
  int nwg = gridDim.x;
  int bid = blockIdx.x;
  int wg = (bid & 7) * (nwg >> 3) + (bid >> 3);  // XCD swizzle (nwg % 8 == 0)
  int tm = wg / nbn, tn = wg % nbn;
  int tid = threadIdx.x;
  int wave = tid >> 6, lane = tid & 63;
  int wr = wave >> 2, wc = wave & 3;  // 2 x 4 wave grid; per-wave C = 128 x 64
  int l15 = lane & 15, g = lane >> 4;
  int nt = K >> 6;

  const unsigned short* Abase = A + (size_t)(tm * 256) * sA;
  const unsigned short* Wbase = W + (size_t)(tn * 256) * sW;
  int srow = tid >> 3;
  int schunk = (tid & 7) ^ (srow & 7);

  f32x4 acc[8][4] = {};
  bf16x8 afrA[2][2], afrB[2][2], bfr[2][4];

  auto stage = [&](int buf, int s, int kt) {
    const unsigned short* base = (s < 2) ? Abase : Wbase;
    int str = (s < 2) ? sA : sW;
    int rbase = (s & 1) * 128;
#pragma unroll
    for (int e = 0; e < 2; ++e) {
      gld16(base + (size_t)(rbase + srow + e * 64) * str + kt * 64 + schunk * 8,
            &lds[buf][s][wave * 512 + e * 4096]);
    }
  };
  auto readB = [&](int buf) {
    const unsigned short* Bh = &lds[buf][2 + (wc >> 1)][0];
#pragma unroll
    for (int kk = 0; kk < 2; ++kk)
#pragma unroll
      for (int j = 0; j < 4; ++j) {
        int br = (wc & 1) * 64 + j * 16 + l15;
        bfr[kk][j] = *(const bf16x8*)&Bh[br * 64 + (((kk * 4 + g) ^ (br & 7)) * 8)];
      }
  };
  auto readA = [&](bf16x8 (&dst)[2][2], int buf, int q) {
    const unsigned short* Ah = &lds[buf][wr][0];
#pragma unroll
    for (int kk = 0; kk < 2; ++kk)
#pragma unroll
      for (int ri = 0; ri < 2; ++ri) {
        int ar = q * 32 + ri * 16 + l15;
        dst[kk][ri] = *(const bf16x8*)&Ah[ar * 64 + (((kk * 4 + g) ^ (ar & 7)) * 8)];
      }
  };
  auto mfma16 = [&](bf16x8 (&af)[2][2], int q) {
    __builtin_amdgcn_s_setprio(1);
#pragma unroll
    for (int kk = 0; kk < 2; ++kk)
#pragma unroll
      for (int ri = 0; ri < 2; ++ri)
#pragma unroll
        for (int j = 0; j < 4; ++j)
          acc[q * 2 + ri][j] = __builtin_amdgcn_mfma_f32_16x16x32_bf16(
              af[kk][ri], bfr[kk][j], acc[q * 2 + ri][j], 0, 0, 0);
    __builtin_amdgcn_s_setprio(0);
  };

  stage(0, 2, 0); stage(0, 3, 0); stage(0, 0, 0); stage(0, 1, 0);
  stage(1, 2, 1); stage(1, 3, 1);
  asm volatile("s_waitcnt vmcnt(4)" ::: "memory");
  __builtin_amdgcn_s_barrier();

  for (int t = 0; t < nt; ++t) {
    int buf = t & 1;
    // phase 0: B frags + afrA(q0) + prefetch afrB(q1)   [no barrier after]
    __builtin_amdgcn_sched_barrier(0);
    if (t + 1 < nt) stage(buf ^ 1, 0, t + 1);
    readB(buf);
    readA(afrA, buf, 0);
    readA(afrB, buf, 1);
    mfma16(afrA, 0);
    // phase 1: prefetch afrA(q2)
    __builtin_amdgcn_sched_barrier(0);
    if (t + 1 < nt) stage(buf ^ 1, 1, t + 1);
    readA(afrA, buf, 2);
    mfma16(afrB, 1);
    __builtin_amdgcn_s_barrier();  // fences readB/readA before slot-2/3 overwrite
    // phase 2: prefetch afrB(q3)   [no barrier after]
    __builtin_amdgcn_sched_barrier(0);
    if (t + 2 < nt) stage(buf, 2, t + 2);
    readA(afrB, buf, 3);
    mfma16(afrA, 2);
    // phase 3: no ds_reads; MFMA covers vmcnt drain
    __builtin_amdgcn_sched_barrier(0);
    if (t + 2 < nt) stage(buf, 3, t + 2);
    mfma16(afrB, 3);
    if (t + 2 < nt) asm volatile("s_waitcnt vmcnt(4)" ::: "memory");
    else asm volatile("s_waitcnt vmcnt(0)" ::: "memory");
    __builtin_amdgcn_s_barrier();  // tile swap
  }

  int row0 = tm * 256 + wr * 128 + g * 4;
  int col0 = tn * 256 + wc * 64 + l15;
#pragma unroll
  for (int i = 0; i < 8; ++i) {
#pragma unroll
    for (int j = 0; j < 4; ++j) {
      int col = col0 + j * 16;
      float bb = (BIAS2 && col >= b2off) ? bias2[col - b2off] : bias[col];
#pragma unroll
      for (int r = 0; r < 4; ++r) {
        int row = row0 + i * 16 + r;
        float v = acc[i][j][r] + bb;
        if (RELU) v = fmaxf(v, 0.0f);
        outB[(size_t)row * N + col] = f2b(v);
      }
    }
  }
}

// ---------- GEMM 256x128 8-wave, BK=64, counted-vmcnt + frag-prefetch ----------
// Same 2-barrier-per-tile scheme as gemm256.
// MODE: 1 = bf16 out + row bias; 2 = fp32 out = resid + v + col bias; 3 = fp32 out += v.
template <int MODE>
__global__ __launch_bounds__(512, 1) void gemm256x128(const unsigned short* __restrict__ A,
                                                      const unsigned short* __restrict__ W,
                                                      const float* __restrict__ bias,
                                                      const float* __restrict__ resid,
                                                      float* __restrict__ outF,
                                                      unsigned short* __restrict__ outB,
                                                      int M, int N, int K, int sA, int sW) {
  __shared__ unsigned short lds[2][3][128 * 64];  // 96 KB
  int nbn = N >> 7;
  int nwg = gridDim.x;
  int bid = blockIdx.x;
  int wg = (bid & 7) * (nwg >> 3) + (bid >> 3);  // XCD swizzle (nwg % 8 == 0)
  int tm = wg / nbn, tn = wg % nbn;
  int tid = threadIdx.x;
  int wave = tid >> 6, lane = tid & 63;
  int wr = wave >> 2, wc = wave & 3;  // per-wave C = 128 rows x 32 cols
  int l15 = lane & 15, g = lane >> 4;
  int nt = K >> 6;

  const unsigned short* Abase = A + (size_t)(tm * 256) * sA;
  const unsigned short* Wbase = W + (size_t)(tn * 128) * sW;
  int srow = tid >> 3;
  int schunk = (tid & 7) ^ (srow & 7);

  f32x4 acc[8][2] = {};
  bf16x8 afrA[2][2], afrB[2][2], bfr[2][2];

  auto stage = [&](int buf, int s, int kt) {
    const unsigned short* base = (s < 2) ? Abase : Wbase;
    int str = (s < 2) ? sA : sW;
    int rbase = (s & 1) * 128;  // s=2 -> 0
#pragma unroll
    for (int e = 0; e < 2; ++e) {
      gld16(base + (size_t)(rbase + srow + e * 64) * str + kt * 64 + schunk * 8,
            &lds[buf][s][wave * 512 + e * 4096]);
    }
  };
  auto readB = [&](int buf) {
    const unsigned short* Bh = &lds[buf][2][0];
#pragma unroll
    for (int kk = 0; kk < 2; ++kk)
#pragma unroll
      for (int j = 0; j < 2; ++j) {
        int br = wc * 32 + j * 16 + l15;
        bfr[kk][j] = *(const bf16x8*)&Bh[br * 64 + (((kk * 4 + g) ^ (br & 7)) * 8)];
      }
  };
  auto readA = [&](bf16x8 (&dst)[2][2], int buf, int q) {
    const unsigned short* Ah = &lds[buf][wr][0];
#pragma unroll
    for (int kk = 0; kk < 2; ++kk)
#pragma unroll
      for (int ri = 0; ri < 2; ++ri) {
        int ar = q * 32 + ri * 16 + l15;
        dst[kk][ri] = *(const bf16x8*)&Ah[ar * 64 + (((kk * 4 + g) ^ (ar & 7)) * 8)];
      }
  };
  auto mfma8 = [&](bf16x8 (&af)[2][2], int q) {
    __builtin_amdgcn_s_setprio(1);
#pragma unroll
    for (int kk = 0; kk < 2; ++kk)
#pragma unroll
      for (int ri = 0; ri < 2; ++ri)
#pragma unroll
        for (int j = 0; j < 2; ++j)
          acc[q * 2 + ri][j] = __builtin_amdgcn_mfma_f32_16x16x32_bf16(
              af[kk][ri], bfr[kk][j], acc[q * 2 + ri][j], 0, 0, 0);
    __builtin_amdgcn_s_setprio(0);
  };

  stage(0, 2, 0); stage(0, 0, 0); stage(0, 1, 0);
  stage(1, 2, 1);
  asm volatile("s_waitcnt vmcnt(2)" ::: "memory");
  __builtin_amdgcn_s_barrier();

  for (int t = 0; t < nt; ++t) {
    int buf = t & 1;
    // phase 0   [no barrier after]
    __builtin_amdgcn_sched_barrier(0);
    if (t + 1 < nt) stage(buf ^ 1, 0, t + 1);
    readB(buf);
    readA(afrA, buf, 0);
    readA(afrB, buf, 1);
    mfma8(afrA, 0);
    // phase 1
    __builtin_amdgcn_sched_barrier(0);
    if (t + 1 < nt) stage(buf ^ 1, 1, t + 1);
    readA(afrA, buf, 2);
    mfma8(afrB, 1);
    __builtin_amdgcn_s_barrier();  // fences readB before slot-2 overwrite
    // phase 2   [no barrier after]
    __builtin_amdgcn_sched_barrier(0);
    if (t + 2 < nt) stage(buf, 2, t + 2);
    readA(afrB, buf, 3);
    mfma8(afrA, 2);
    // phase 3: no ds_reads
    __builtin_amdgcn_sched_barrier(0);
    mfma8(afrB, 3);
    if (t + 2 < nt) asm volatile("s_waitcnt vmcnt(2)" ::: "memory");
    else asm volatile("s_waitcnt vmcnt(0)" ::: "memory");
    __builtin_amdgcn_s_barrier();  // tile swap
  }

  int row0 = tm * 256 + wr * 128 + g * 4;
  int col0 = tn * 128 + wc * 32 + l15;
#pragma unroll
  for (int i = 0; i < 8; ++i) {
#pragma unroll
    for (int j = 0; j < 2; ++j) {
      int col = col0 + j * 16;
      float cb = (MODE == 2) ? bias[col] : 0.0f;
#pragma unroll
      for (int r = 0; r < 4; ++r) {
        int row = row0 + i * 16 + r;
        size_t idx = (size_t)row * N + col;
        float v = acc[i][j][r];
        if (MODE == 1) outB[idx] = f2b(v + bias[row]);
        else if (MODE == 2) outF[idx] = resid[idx] + v + cb;
        else outF[idx] += v;
      }
    }
  }
}

// ---------- flash attention v9 (exact R13 form, session-best 68us): ----------
// 8 waves x 2 q-sets (256 q-rows/block), no-max softmax, 64-key double-buffered tiles.
__global__ __launch_bounds__(512, 4) void attn_fwd9(const unsigned short* __restrict__ QK,
                                                    const unsigned short* __restrict__ Vt,
                                                    const int* __restrict__ mask,
                                                    unsigned short* __restrict__ O) {
  __shared__ unsigned short Kl[2][64 * 64];
  __shared__ unsigned short Vl[2][64 * 64];
  __shared__ float biasl[1024];
  int bid = blockIdx.x;
  int wg = (bid & 7) * 64 + (bid >> 3);  // XCD swizzle (nwg = 512)
  int qt = wg & 3, bh = wg >> 2;
  int b = bh >> 4, h = bh & 15;
  int tid = threadIdx.x, wave = tid >> 6, lane = tid & 63;
  int l15 = lane & 15, g = lane >> 4;
  int q0 = qt * 256;

  for (int i = tid; i < 1024; i += 512)
    biasl[i] = (mask[b * 1024 + i] == 0) ? -1.4426950e9f : 0.0f;

  const unsigned short* QrowA = QK + ((size_t)(b * 1024 + q0 + wave * 16 + l15)) * 2048 + h * 64;
  const unsigned short* QrowB = QrowA + (size_t)128 * 2048;
  bf16x8 qa0 = *(const bf16x8*)(QrowA + g * 8);
  bf16x8 qa1 = *(const bf16x8*)(QrowA + 32 + g * 8);
  bf16x8 qb0 = *(const bf16x8*)(QrowB + g * 8);
  bf16x8 qb1 = *(const bf16x8*)(QrowB + 32 + g * 8);

  float l_a = 0.0f, l_b = 0.0f;   // lane-partial softmax denominators
  f32x4 oa[4] = {}, ob[4] = {};   // o[dt][r] = O[q][d = dt*16 + g*4 + r]

  int srow = tid >> 3;                // 0..63: staged row
  int clog = (tid & 7) ^ (srow & 7);  // inverse-swizzled chunk
  int h7 = l15 & 7;
  const float SC = 0.125f * 1.44269504f;  // 1/sqrt(64) * log2(e)

  auto stageKV = [&](int buf, int kt) {
    gld16(QK + ((size_t)(b * 1024 + kt * 64 + srow)) * 2048 + 1024 + h * 64 + clog * 8,
          &Kl[buf][(wave * 8) * 64]);
    gld16(Vt + ((size_t)(h * 64 + srow)) * 8192 + b * 1024 + kt * 64 + clog * 8,
          &Vl[buf][(wave * 8) * 64]);
  };

  stageKV(0, 0);
  __syncthreads();
  int cur = 0;

  for (int kt = 0; kt < 16; ++kt) {
    if (kt < 15) stageKV(cur ^ 1, kt + 1);

    // S^T = mfma(A=K, B=Q): one K-frag pair feeds both q-sets
    f32x4 sa[4], sb[4];
    __builtin_amdgcn_s_setprio(1);
#pragma unroll
    for (int j = 0; j < 4; ++j) {
      int kr = j * 16 + l15;
      bf16x8 ka = *(const bf16x8*)&Kl[cur][kr * 64 + ((g ^ h7) * 8)];
      bf16x8 kb = *(const bf16x8*)&Kl[cur][kr * 64 + (((4 + g) ^ h7) * 8)];
      f32x4 z = {};
      sa[j] = __builtin_amdgcn_mfma_f32_16x16x32_bf16(ka, qa0, z, 0, 0, 0);
      sa[j] = __builtin_amdgcn_mfma_f32_16x16x32_bf16(kb, qa1, sa[j], 0, 0, 0);
      sb[j] = __builtin_amdgcn_mfma_f32_16x16x32_bf16(ka, qb0, z, 0, 0, 0);
      sb[j] = __builtin_amdgcn_mfma_f32_16x16x32_bf16(kb, qb1, sb[j], 0, 0, 0);
    }
    __builtin_amdgcn_s_setprio(0);

    // P = exp2(score*SC + maskbias), lane-partial l; pack both sets
    union U8 { uint32_t u[4]; bf16x8 v; } pa[2], pb[2];
#pragma unroll
    for (int j = 0; j < 4; ++j) {
      float4 b4 = *(const float4*)&biasl[kt * 64 + j * 16 + g * 4];
      float ea0 = exp2_fast(sa[j][0] * SC + b4.x);
      float ea1 = exp2_fast(sa[j][1] * SC + b4.y);
      float ea2 = exp2_fast(sa[j][2] * SC + b4.z);
      float ea3 = exp2_fast(sa[j][3] * SC + b4.w);
      l_a += (ea0 + ea1) + (ea2 + ea3);
      pa[j >> 1].u[(j & 1) * 2 + 0] = cvtpk(ea0, ea1);
      pa[j >> 1].u[(j & 1) * 2 + 1] = cvtpk(ea2, ea3);
      float eb0 = exp2_fast(sb[j][0] * SC + b4.x);
      float eb1 = exp2_fast(sb[j][1] * SC + b4.y);
      float eb2 = exp2_fast(sb[j][2] * SC + b4.z);
      float eb3 = exp2_fast(sb[j][3] * SC + b4.w);
      l_b += (eb0 + eb1) + (eb2 + eb3);
      pb[j >> 1].u[(j & 1) * 2 + 0] = cvtpk(eb0, eb1);
      pb[j >> 1].u[(j & 1) * 2 + 1] = cvtpk(eb2, eb3);
    }

    // PV: one V-frag feeds both q-sets
    __builtin_amdgcn_s_setprio(1);
#pragma unroll
    for (int kk = 0; kk < 2; ++kk) {
#pragma unroll
      for (int dt = 0; dt < 4; ++dt) {
        int vr = dt * 16 + l15;
        uint2 lo = *(const uint2*)&Vl[cur][vr * 64 + (((4 * kk + (g >> 1)) ^ h7) * 8) + (g & 1) * 4];
        uint2 hi = *(const uint2*)&Vl[cur][vr * 64 + (((4 * kk + 2 + (g >> 1)) ^ h7) * 8) + (g & 1) * 4];
        U8 vbu;
        vbu.u[0] = lo.x; vbu.u[1] = lo.y; vbu.u[2] = hi.x; vbu.u[3] = hi.y;
        oa[dt] = __builtin_amdgcn_mfma_f32_16x16x32_bf16(vbu.v, pa[kk].v, oa[dt], 0, 0, 0);
        ob[dt] = __builtin_amdgcn_mfma_f32_16x16x32_bf16(vbu.v, pb[kk].v, ob[dt], 0, 0, 0);
      }
    }
    __builtin_amdgcn_s_setprio(0);

    __syncthreads();
    cur ^= 1;
  }

  // final l reduce across the 4 lane-copies of each q, then lane-local epilogue
  l_a += __shfl_xor(l_a, 16);
  l_a += __shfl_xor(l_a, 32);
  l_b += __shfl_xor(l_b, 16);
  l_b += __shfl_xor(l_b, 32);
  float inva = 1.0f / l_a, invb = 1.0f / l_b;
  size_t orowA = ((size_t)(b * 1024 + q0 + wave * 16 + l15)) * 1024 + h * 64;
  size_t orowB = orowA + (size_t)128 * 1024;
#pragma unroll
  for (int dt = 0; dt < 4; ++dt) {
    uint2 wa, wb;
    wa.x = cvtpk(oa[dt][0] * inva, oa[dt][1] * inva);
    wa.y = cvtpk(oa[dt][2] * inva, oa[dt][3] * inva);
    *(uint2*)&O[orowA + dt * 16 + g * 4] = wa;
    wb.x = cvtpk(ob[dt][0] * invb, ob[dt][1] * invb);
    wb.y = cvtpk(ob[dt][2] * invb, ob[dt][3] * invb);
    *(uint2*)&O[orowB + dt * 16 + g * 4] = wb;
  }
}

// ---------- launch ----------
extern "C" void kernel_launch(void* const* d_in, const int* in_sizes, int n_in,
                              void* d_out, int out_size, void* d_ws, size_t ws_size,
                              hipStream_t stream) {
  const float* X = (const float*)d_in[0];
  const int* mask = (const int*)d_in[1];
  const float* wq = (const float*)d_in[2];
  const float* bq = (const float*)d_in[3];
  const float* wk = (const float*)d_in[4];
  const float* bk = (const float*)d_in[5];
  const float* wv = (const float*)d_in[6];
  const float* bv = (const float*)d_in[7];
  const float* wo = (const float*)d_in[8];
  const float* bo = (const float*)d_in[9];
  const float* w1 = (const float*)d_in[10];
  const float* b1 = (const float*)d_in[11];
  const float* w2 = (const float*)d_in[12];
  const float* b2 = (const float*)d_in[13];
  const float* ln1a = (const float*)d_in[14];
  const float* ln1b = (const float*)d_in[15];
  const float* ln2a = (const float*)d_in[16];
  const float* ln2b = (const float*)d_in[17];
  float* out = (float*)d_out;
  char* ws = (char*)d_ws;
  const size_t MB = 1024 * 1024;

  // layout (88MB): [0,8) w1_b | [8,16) w2_b | [16,20) wqk_b | [20,22) wv_b |
  // [22,24) wo_b | [24,40) xn (LN1 out -> attn O -> LN2 out) | [40,72) QKb -> hb |
  // [72,88) Vtb
  unsigned short* w1_b = (unsigned short*)(ws + 0 * MB);
  unsigned short* w2_b = (unsigned short*)(ws + 8 * MB);
  unsigned short* wqk_b = (unsigned short*)(ws + 16 * MB);
  unsigned short* wv_b = (unsigned short*)(ws + 20 * MB);
  unsigned short* wo_b = (unsigned short*)(ws + 22 * MB);
  unsigned short* xn = (unsigned short*)(ws + 24 * MB);
  unsigned short* QKb = (unsigned short*)(ws + 40 * MB);
  unsigned short* Vtb = (unsigned short*)(ws + 72 * MB);
  unsigned short* hb = QKb;

  // all weights -> bf16 in one launch (wq,wk stacked into wqk_b)
  cast_all<<<12288, 256, 0, stream>>>(w1, w2, wq, wk, wv, wo, w1_b, w2_b, wqk_b, wv_b, wo_b);

  // LN1
  ln_bf16<<<8192, 256, 0, stream>>>(X, xn, ln1a, ln1b);
  // fused Q+K projection: QK[token][2048]  (256^2 tile, grid 256 = 1/CU)
  gemm256<0, 1><<<256, 512, 0, stream>>>(xn, wqk_b, bq, bk, 1024, QKb,
                                         8192, 2048, 1024, 1024, 1024);
  // V transposed: Vt[hd][token] = wv @ xn^T + bv (row bias)  (256x128, grid 256)
  gemm256x128<1><<<256, 512, 0, stream>>>(wv_b, xn, bv, nullptr, nullptr, Vtb,
                                          1024, 8192, 1024, 1024, 1024);
  // attention (writes O into xn buffer); 512 blocks x 512 thr = 2 blocks/CU
  attn_fwd9<<<512, 512, 0, stream>>>(QKb, Vtb, mask, xn);
  // out = X + O @ wo^T + bo  (256x128, grid 256)
  gemm256x128<2><<<256, 512, 0, stream>>>(xn, wo_b, bo, X, out, nullptr,
                                          8192, 1024, 1024, 1024, 1024);
  // LN2 (reads out, writes into xn region)
  ln_bf16<<<8192, 256, 0, stream>>>(out, xn, ln2a, ln2b);
  // FFN chunked along hidden dim: h half = [8192][2048] in hb (QKb region)
  for (int hc = 0; hc < 2; ++hc) {
    // h = relu(xn @ w1[hc*2048:(hc+1)*2048]^T + b1[hc*2048:])  (256^2)
    gemm256<1, 0><<<256, 512, 0, stream>>>(xn, w1_b + (size_t)hc * 2048 * 1024,
                                           b1 + hc * 2048, nullptr, 0, hb,
                                           8192, 2048, 1024, 1024, 1024);
    if (hc == 0)  // out = out + b2 + h_half @ w2[:, 0:2048]^T  (256x128)
      gemm256x128<2><<<256, 512, 0, stream>>>(hb, w2_b, b2, out, out, nullptr,
                                              8192, 1024, 2048, 2048, 4096);
    else          // out += h_half @ w2[:, 2048:4096]^T  (256x128)
      gemm256x128<3><<<256, 512, 0, stream>>>(hb, w2_b + 2048, nullptr, nullptr, out, nullptr,
                                              8192, 1024, 2048, 2048, 4096);
  }
}

// Round 18
// 344.957 us; speedup vs baseline: 1.2634x; 1.0021x over previous
//
#include <hip/hip_runtime.h>
#include <cstdint>
#include <cstddef>

// ---------- types ----------
typedef float f32x4 __attribute__((ext_vector_type(4)));
typedef short bf16x8 __attribute__((ext_vector_type(8)));

typedef __attribute__((address_space(1))) void void_g;
typedef __attribute__((address_space(3))) void void_l;

__device__ __forceinline__ void gld16(const void* g, void* l) {
  // async global->LDS, 16B per lane; LDS dest = wave-uniform base + lane*16
  __builtin_amdgcn_global_load_lds((void_g*)g, (void_l*)l, 16, 0, 0);
}

__device__ __forceinline__ unsigned short f2b(float f) {
  union { float f; uint32_t u; } c; c.f = f;
  uint32_t u = c.u;
  return (unsigned short)((u + 0x7fffu + ((u >> 16) & 1u)) >> 16);  // RNE
}

__device__ __forceinline__ uint32_t cvtpk(float lo, float hi) {
  uint32_t r;
  asm("v_cvt_pk_bf16_f32 %0, %1, %2" : "=v"(r) : "v"(lo), "v"(hi));
  return r;  // low16 = bf16(lo), high16 = bf16(hi)
}

__device__ __forceinline__ float exp2_fast(float x) {
  return __builtin_exp2f(x);  // lowers to v_exp_f32 (2^x) on gfx950
}

// ---------- fused prologue: all weight casts + LN1 in ONE launch ----------
// blocks [0,12288): fp32->bf16 weight casts; blocks [12288,20480): LN1 rows.
// The two phases touch disjoint data and overlap on the GPU instead of
// running serially as separate dispatches.
__global__ __launch_bounds__(256) void prep_all(const float* __restrict__ w1,
                                                const float* __restrict__ w2,
                                                const float* __restrict__ wq,
                                                const float* __restrict__ wk,
                                                const float* __restrict__ wv,
                                                const float* __restrict__ wo,
                                                unsigned short* __restrict__ d1,
                                                unsigned short* __restrict__ d2,
                                                unsigned short* __restrict__ dqk,
                                                unsigned short* __restrict__ dv,
                                                unsigned short* __restrict__ dod,
                                                const float* __restrict__ X,
                                                unsigned short* __restrict__ xnout,
                                                const float* __restrict__ alpha,
                                                const float* __restrict__ beta) {
  int blk = blockIdx.x;
  int tid = threadIdx.x;
  if (blk < 12288) {
    const float* s;
    unsigned short* d;
    int off;
    if (blk < 4096) { s = w1; d = d1; off = blk; }
    else if (blk < 8192) { s = w2; d = d2; off = blk - 4096; }
    else if (blk < 9216) { s = wq; d = dqk; off = blk - 8192; }
    else if (blk < 10240) { s = wk; d = dqk + (1 << 20); off = blk - 9216; }
    else if (blk < 11264) { s = wv; d = dv; off = blk - 10240; }
    else { s = wo; d = dod; off = blk - 11264; }
    int i = off * 256 + tid;
    float4 v = ((const float4*)s)[i];
    ushort4 o;
    o.x = f2b(v.x); o.y = f2b(v.y); o.z = f2b(v.z); o.w = f2b(v.w);
    ((ushort4*)d)[i] = o;
    return;
  }
  // LN1 on row (blk - 12288)
  int row = blk - 12288;
  float4 v = ((const float4*)(X + (size_t)row * 1024))[tid];
  float s = v.x + v.y + v.z + v.w;
  float q = v.x * v.x + v.y * v.y + v.z * v.z + v.w * v.w;
#pragma unroll
  for (int m = 1; m < 64; m <<= 1) { s += __shfl_xor(s, m); q += __shfl_xor(q, m); }
  __shared__ float red[8];
  int wave = tid >> 6;
  if ((tid & 63) == 0) { red[wave] = s; red[4 + wave] = q; }
  __syncthreads();
  s = red[0] + red[1] + red[2] + red[3];
  q = red[4] + red[5] + red[6] + red[7];
  float mean = s * (1.0f / 1024.0f);
  float var = fmaxf((q - 1024.0f * mean * mean) * (1.0f / 1023.0f), 0.0f);
  float inv = alpha[0] / (sqrtf(var) + 1e-6f);
  float b = beta[0];
  ushort4 o;
  o.x = f2b((v.x - mean) * inv + b);
  o.y = f2b((v.y - mean) * inv + b);
  o.z = f2b((v.z - mean) * inv + b);
  o.w = f2b((v.w - mean) * inv + b);
  ((ushort4*)(xnout + (size_t)row * 1024))[tid] = o;
}

// ---------- LayerNorm (unbiased std, scalar alpha/beta) -> bf16 ----------
__global__ __launch_bounds__(256) void ln_bf16(const float* __restrict__ X,
                                               unsigned short* __restrict__ out,
                                               const float* __restrict__ alpha,
                                               const float* __restrict__ beta) {
  int row = blockIdx.x;
  int tid = threadIdx.x;
  float4 v = ((const float4*)(X + (size_t)row * 1024))[tid];
  float s = v.x + v.y + v.z + v.w;
  float q = v.x * v.x + v.y * v.y + v.z * v.z + v.w * v.w;
#pragma unroll
  for (int m = 1; m < 64; m <<= 1) { s += __shfl_xor(s, m); q += __shfl_xor(q, m); }
  __shared__ float red[8];
  int wave = tid >> 6;
  if ((tid & 63) == 0) { red[wave] = s; red[4 + wave] = q; }
  __syncthreads();
  s = red[0] + red[1] + red[2] + red[3];
  q = red[4] + red[5] + red[6] + red[7];
  float mean = s * (1.0f / 1024.0f);
  float var = fmaxf((q - 1024.0f * mean * mean) * (1.0f / 1023.0f), 0.0f);
  float inv = alpha[0] / (sqrtf(var) + 1e-6f);
  float b = beta[0];
  ushort4 o;
  o.x = f2b((v.x - mean) * inv + b);
  o.y = f2b((v.y - mean) * inv + b);
  o.z = f2b((v.z - mean) * inv + b);
  o.w = f2b((v.w - mean) * inv + b);
  ((ushort4*)(out + (size_t)row * 1024))[tid] = o;
}

// ---------- GEMM 256x256 8-wave, BK=64, counted-vmcnt + frag-prefetch pipeline ----------
// 2 barriers per K-tile (hazard-audited): barrier after phase 1 fences readB/readA
// of slots overwritten by phase-2/3 stages; barrier after phase 3 (with counted
// vmcnt) completes the tile swap. Barriers after phases 0 and 2 removed (dead).
template <int RELU, int BIAS2>
__global__ __launch_bounds__(512, 1) void gemm256(const unsigned short* __restrict__ A,
                                                  const unsigned short* __restrict__ W,
                                                  const float* __restrict__ bias,
                                                  const float* __restrict__ bias2, int b2off,
                                                  unsigned short* __restrict__ outB,
                                                  int M, int N, int K, int sA, int sW) {
  __shared__ unsigned short lds[2][4][128 * 64];  // 128 KB
  int nbn = N >> 8;
  int nwg = gridDim.x;
  int bid = blockIdx.x;
  int wg = (bid & 7) * (nwg >> 3) + (bid >> 3);  // XCD swizzle (nwg % 8 == 0)
  int tm = wg / nbn, tn = wg % nbn;
  int tid = threadIdx.x;
  int wave = tid >> 6, lane = tid & 63;
  int wr = wave >> 2, wc = wave & 3;  // 2 x 4 wave grid; per-wave C = 128 x 64
  int l15 = lane & 15, g = lane >> 4;
  int nt = K >> 6;

  const unsigned short* Abase = A + (size_t)(tm * 256) * sA;
  const unsigned short* Wbase = W + (size_t)(tn * 256) * sW;
  int srow = tid >> 3;
  int schunk = (tid & 7) ^ (srow & 7);

  f32x4 acc[8][4] = {};
  bf16x8 afrA[2][2], afrB[2][2], bfr[2][4];

  auto stage = [&](int buf, int s, int kt) {
    const unsigned short* base = (s < 2) ? Abase : Wbase;
    int str = (s < 2) ? sA : sW;
    int rbase = (s & 1) * 128;
#pragma unroll
    for (int e = 0; e < 2; ++e) {
      gld16(base + (size_t)(rbase + srow + e * 64) * str + kt * 64 + schunk * 8,
            &lds[buf][s][wave * 512 + e * 4096]);
    }
  };
  auto readB = [&](int buf) {
    const unsigned short* Bh = &lds[buf][2 + (wc >> 1)][0];
#pragma unroll
    for (int kk = 0; kk < 2; ++kk)
#pragma unroll
      for (int j = 0; j < 4; ++j) {
        int br = (wc & 1) * 64 + j * 16 + l15;
        bfr[kk][j] = *(const bf16x8*)&Bh[br * 64 + (((kk * 4 + g) ^ (br & 7)) * 8)];
      }
  };
  auto readA = [&](bf16x8 (&dst)[2][2], int buf, int q) {
    const unsigned short* Ah = &lds[buf][wr][0];
#pragma unroll
    for (int kk = 0; kk < 2; ++kk)
#pragma unroll
      for (int ri = 0; ri < 2; ++ri) {
        int ar = q * 32 + ri * 16 + l15;
        dst[kk][ri] = *(const bf16x8*)&Ah[ar * 64 + (((kk * 4 + g) ^ (ar & 7)) * 8)];
      }
  };
  auto mfma16 = [&](bf16x8 (&af)[2][2], int q) {
    __builtin_amdgcn_s_setprio(1);
#pragma unroll
    for (int kk = 0; kk < 2; ++kk)
#pragma unroll
      for (int ri = 0; ri < 2; ++ri)
#pragma unroll
        for (int j = 0; j < 4; ++j)
          acc[q * 2 + ri][j] = __builtin_amdgcn_mfma_f32_16x16x32_bf16(
              af[kk][ri], bfr[kk][j], acc[q * 2 + ri][j], 0, 0, 0);
    __builtin_amdgcn_s_setprio(0);
  };

  stage(0, 2, 0); stage(0, 3, 0); stage(0, 0, 0); stage(0, 1, 0);
  stage(1, 2, 1); stage(1, 3, 1);
  asm volatile("s_waitcnt vmcnt(4)" ::: "memory");
  __builtin_amdgcn_s_barrier();

  for (int t = 0; t < nt; ++t) {
    int buf = t & 1;
    // phase 0: B frags + afrA(q0) + prefetch afrB(q1)   [no barrier after]
    __builtin_amdgcn_sched_barrier(0);
    if (t + 1 < nt) stage(buf ^ 1, 0, t + 1);
    readB(buf);
    readA(afrA, buf, 0);
    readA(afrB, buf, 1);
    mfma16(afrA, 0);
    // phase 1: prefetch afrA(q2)
    __builtin_amdgcn_sched_barrier(0);
    if (t + 1 < nt) stage(buf ^ 1, 1, t + 1);
    readA(afrA, buf, 2);
    mfma16(afrB, 1);
    __builtin_amdgcn_s_barrier();  // fences readB/readA before slot-2/3 overwrite
    // phase 2: prefetch afrB(q3)   [no barrier after]
    __builtin_amdgcn_sched_barrier(0);
    if (t + 2 < nt) stage(buf, 2, t + 2);
    readA(afrB, buf, 3);
    mfma16(afrA, 2);
    // phase 3: no ds_reads; MFMA covers vmcnt drain
    __builtin_amdgcn_sched_barrier(0);
    if (t + 2 < nt) stage(buf, 3, t + 2);
    mfma16(afrB, 3);
    if (t + 2 < nt) asm volatile("s_waitcnt vmcnt(4)" ::: "memory");
    else asm volatile("s_waitcnt vmcnt(0)" ::: "memory");
    __builtin_amdgcn_s_barrier();  // tile swap
  }

  int row0 = tm * 256 + wr * 128 + g * 4;
  int col0 = tn * 256 + wc * 64 + l15;
#pragma unroll
  for (int i = 0; i < 8; ++i) {
#pragma unroll
    for (int j = 0; j < 4; ++j) {
      int col = col0 + j * 16;
      float bb = (BIAS2 && col >= b2off) ? bias2[col - b2off] : bias[col];
#pragma unroll
      for (int r = 0; r < 4; ++r) {
        int row = row0 + i * 16 + r;
        float v = acc[i][j][r] + bb;
        if (RELU) v = fmaxf(v, 0.0f);
        outB[(size_t)row * N + col] = f2b(v);
      }
    }
  }
}

// ---------- GEMM 256x128 8-wave, BK=64, counted-vmcnt + frag-prefetch ----------
// Same 2-barrier-per-tile scheme as gemm256.
// MODE: 1 = bf16 out + row bias; 2 = fp32 out = resid + v + col bias; 3 = fp32 out += v.
template <int MODE>
__global__ __launch_bounds__(512, 1) void gemm256x128(const unsigned short* __restrict__ A,
                                                      const unsigned short* __restrict__ W,
                                                      const float* __restrict__ bias,
                                                      const float* __restrict__ resid,
                                                      float* __restrict__ outF,
                                                      unsigned short* __restrict__ outB,
                                                      int M, int N, int K, int sA, int sW) {
  __shared__ unsigned short lds[2][3][128 * 64];  // 96 KB
  int nbn = N >> 7;
  int nwg = gridDim.x;
  int bid = blockIdx.x;
  int wg = (bid & 7) * (nwg >> 3) + (bid >> 3);  // XCD swizzle (nwg % 8 == 0)
  int tm = wg / nbn, tn = wg % nbn;
  int tid = threadIdx.x;
  int wave = tid >> 6, lane = tid & 63;
  int wr = wave >> 2, wc = wave & 3;  // per-wave C = 128 rows x 32 cols
  int l15 = lane & 15, g = lane >> 4;
  int nt = K >> 6;

  const unsigned short* Abase = A + (size_t)(tm * 256) * sA;
  const unsigned short* Wbase = W + (size_t)(tn * 128) * sW;
  int srow = tid >> 3;
  int schunk = (tid & 7) ^ (srow & 7);

  f32x4 acc[8][2] = {};
  bf16x8 afrA[2][2], afrB[2][2], bfr[2][2];

  auto stage = [&](int buf, int s, int kt) {
    const unsigned short* base = (s < 2) ? Abase : Wbase;
    int str = (s < 2) ? sA : sW;
    int rbase = (s & 1) * 128;  // s=2 -> 0
#pragma unroll
    for (int e = 0; e < 2; ++e) {
      gld16(base + (size_t)(rbase + srow + e * 64) * str + kt * 64 + schunk * 8,
            &lds[buf][s][wave * 512 + e * 4096]);
    }
  };
  auto readB = [&](int buf) {
    const unsigned short* Bh = &lds[buf][2][0];
#pragma unroll
    for (int kk = 0; kk < 2; ++kk)
#pragma unroll
      for (int j = 0; j < 2; ++j) {
        int br = wc * 32 + j * 16 + l15;
        bfr[kk][j] = *(const bf16x8*)&Bh[br * 64 + (((kk * 4 + g) ^ (br & 7)) * 8)];
      }
  };
  auto readA = [&](bf16x8 (&dst)[2][2], int buf, int q) {
    const unsigned short* Ah = &lds[buf][wr][0];
#pragma unroll
    for (int kk = 0; kk < 2; ++kk)
#pragma unroll
      for (int ri = 0; ri < 2; ++ri) {
        int ar = q * 32 + ri * 16 + l15;
        dst[kk][ri] = *(const bf16x8*)&Ah[ar * 64 + (((kk * 4 + g) ^ (ar & 7)) * 8)];
      }
  };
  auto mfma8 = [&](bf16x8 (&af)[2][2], int q) {
    __builtin_amdgcn_s_setprio(1);
#pragma unroll
    for (int kk = 0; kk < 2; ++kk)
#pragma unroll
      for (int ri = 0; ri < 2; ++ri)
#pragma unroll
        for (int j = 0; j < 2; ++j)
          acc[q * 2 + ri][j] = __builtin_amdgcn_mfma_f32_16x16x32_bf16(
              af[kk][ri], bfr[kk][j], acc[q * 2 + ri][j], 0, 0, 0);
    __builtin_amdgcn_s_setprio(0);
  };

  stage(0, 2, 0); stage(0, 0, 0); stage(0, 1, 0);
  stage(1, 2, 1);
  asm volatile("s_waitcnt vmcnt(2)" ::: "memory");
  __builtin_amdgcn_s_barrier();

  for (int t = 0; t < nt; ++t) {
    int buf = t & 1;
    // phase 0   [no barrier after]
    __builtin_amdgcn_sched_barrier(0);
    if (t + 1 < nt) stage(buf ^ 1, 0, t + 1);
    readB(buf);
    readA(afrA, buf, 0);
    readA(afrB, buf, 1);
    mfma8(afrA, 0);
    // phase 1
    __builtin_amdgcn_sched_barrier(0);
    if (t + 1 < nt) stage(buf ^ 1, 1, t + 1);
    readA(afrA, buf, 2);
    mfma8(afrB, 1);
    __builtin_amdgcn_s_barrier();  // fences readB before slot-2 overwrite
    // phase 2   [no barrier after]
    __builtin_amdgcn_sched_barrier(0);
    if (t + 2 < nt) stage(buf, 2, t + 2);
    readA(afrB, buf, 3);
    mfma8(afrA, 2);
    // phase 3: no ds_reads
    __builtin_amdgcn_sched_barrier(0);
    mfma8(afrB, 3);
    if (t + 2 < nt) asm volatile("s_waitcnt vmcnt(2)" ::: "memory");
    else asm volatile("s_waitcnt vmcnt(0)" ::: "memory");
    __builtin_amdgcn_s_barrier();  // tile swap
  }

  int row0 = tm * 256 + wr * 128 + g * 4;
  int col0 = tn * 128 + wc * 32 + l15;
#pragma unroll
  for (int i = 0; i < 8; ++i) {
#pragma unroll
    for (int j = 0; j < 2; ++j) {
      int col = col0 + j * 16;
      float cb = (MODE == 2) ? bias[col] : 0.0f;
#pragma unroll
      for (int r = 0; r < 4; ++r) {
        int row = row0 + i * 16 + r;
        size_t idx = (size_t)row * N + col;
        float v = acc[i][j][r];
        if (MODE == 1) outB[idx] = f2b(v + bias[row]);
        else if (MODE == 2) outF[idx] = resid[idx] + v + cb;
        else outF[idx] += v;
      }
    }
  }
}

// ---------- flash attention v9 (exact R13 form, session-best 68us): ----------
// 8 waves x 2 q-sets (256 q-rows/block), no-max softmax, 64-key double-buffered tiles.
__global__ __launch_bounds__(512, 4) void attn_fwd9(const unsigned short* __restrict__ QK,
                                                    const unsigned short* __restrict__ Vt,
                                                    const int* __restrict__ mask,
                                                    unsigned short* __restrict__ O) {
  __shared__ unsigned short Kl[2][64 * 64];
  __shared__ unsigned short Vl[2][64 * 64];
  __shared__ float biasl[1024];
  int bid = blockIdx.x;
  int wg = (bid & 7) * 64 + (bid >> 3);  // XCD swizzle (nwg = 512)
  int qt = wg & 3, bh = wg >> 2;
  int b = bh >> 4, h = bh & 15;
  int tid = threadIdx.x, wave = tid >> 6, lane = tid & 63;
  int l15 = lane & 15, g = lane >> 4;
  int q0 = qt * 256;

  for (int i = tid; i < 1024; i += 512)
    biasl[i] = (mask[b * 1024 + i] == 0) ? -1.4426950e9f : 0.0f;

  const unsigned short* QrowA = QK + ((size_t)(b * 1024 + q0 + wave * 16 + l15)) * 2048 + h * 64;
  const unsigned short* QrowB = QrowA + (size_t)128 * 2048;
  bf16x8 qa0 = *(const bf16x8*)(QrowA + g * 8);
  bf16x8 qa1 = *(const bf16x8*)(QrowA + 32 + g * 8);
  bf16x8 qb0 = *(const bf16x8*)(QrowB + g * 8);
  bf16x8 qb1 = *(const bf16x8*)(QrowB + 32 + g * 8);

  float l_a = 0.0f, l_b = 0.0f;   // lane-partial softmax denominators
  f32x4 oa[4] = {}, ob[4] = {};   // o[dt][r] = O[q][d = dt*16 + g*4 + r]

  int srow = tid >> 3;                // 0..63: staged row
  int clog = (tid & 7) ^ (srow & 7);  // inverse-swizzled chunk
  int h7 = l15 & 7;
  const float SC = 0.125f * 1.44269504f;  // 1/sqrt(64) * log2(e)

  auto stageKV = [&](int buf, int kt) {
    gld16(QK + ((size_t)(b * 1024 + kt * 64 + srow)) * 2048 + 1024 + h * 64 + clog * 8,
          &Kl[buf][(wave * 8) * 64]);
    gld16(Vt + ((size_t)(h * 64 + srow)) * 8192 + b * 1024 + kt * 64 + clog * 8,
          &Vl[buf][(wave * 8) * 64]);
  };

  stageKV(0, 0);
  __syncthreads();
  int cur = 0;

  for (int kt = 0; kt < 16; ++kt) {
    if (kt < 15) stageKV(cur ^ 1, kt + 1);

    // S^T = mfma(A=K, B=Q): one K-frag pair feeds both q-sets
    f32x4 sa[4], sb[4];
    __builtin_amdgcn_s_setprio(1);
#pragma unroll
    for (int j = 0; j < 4; ++j) {
      int kr = j * 16 + l15;
      bf16x8 ka = *(const bf16x8*)&Kl[cur][kr * 64 + ((g ^ h7) * 8)];
      bf16x8 kb = *(const bf16x8*)&Kl[cur][kr * 64 + (((4 + g) ^ h7) * 8)];
      f32x4 z = {};
      sa[j] = __builtin_amdgcn_mfma_f32_16x16x32_bf16(ka, qa0, z, 0, 0, 0);
      sa[j] = __builtin_amdgcn_mfma_f32_16x16x32_bf16(kb, qa1, sa[j], 0, 0, 0);
      sb[j] = __builtin_amdgcn_mfma_f32_16x16x32_bf16(ka, qb0, z, 0, 0, 0);
      sb[j] = __builtin_amdgcn_mfma_f32_16x16x32_bf16(kb, qb1, sb[j], 0, 0, 0);
    }
    __builtin_amdgcn_s_setprio(0);

    // P = exp2(score*SC + maskbias), lane-partial l; pack both sets
    union U8 { uint32_t u[4]; bf16x8 v; } pa[2], pb[2];
#pragma unroll
    for (int j = 0; j < 4; ++j) {
      float4 b4 = *(const float4*)&biasl[kt * 64 + j * 16 + g * 4];
      float ea0 = exp2_fast(sa[j][0] * SC + b4.x);
      float ea1 = exp2_fast(sa[j][1] * SC + b4.y);
      float ea2 = exp2_fast(sa[j][2] * SC + b4.z);
      float ea3 = exp2_fast(sa[j][3] * SC + b4.w);
      l_a += (ea0 + ea1) + (ea2 + ea3);
      pa[j >> 1].u[(j & 1) * 2 + 0] = cvtpk(ea0, ea1);
      pa[j >> 1].u[(j & 1) * 2 + 1] = cvtpk(ea2, ea3);
      float eb0 = exp2_fast(sb[j][0] * SC + b4.x);
      float eb1 = exp2_fast(sb[j][1] * SC + b4.y);
      float eb2 = exp2_fast(sb[j][2] * SC + b4.z);
      float eb3 = exp2_fast(sb[j][3] * SC + b4.w);
      l_b += (eb0 + eb1) + (eb2 + eb3);
      pb[j >> 1].u[(j & 1) * 2 + 0] = cvtpk(eb0, eb1);
      pb[j >> 1].u[(j & 1) * 2 + 1] = cvtpk(eb2, eb3);
    }

    // PV: one V-frag feeds both q-sets
    __builtin_amdgcn_s_setprio(1);
#pragma unroll
    for (int kk = 0; kk < 2; ++kk) {
#pragma unroll
      for (int dt = 0; dt < 4; ++dt) {
        int vr = dt * 16 + l15;
        uint2 lo = *(const uint2*)&Vl[cur][vr * 64 + (((4 * kk + (g >> 1)) ^ h7) * 8) + (g & 1) * 4];
        uint2 hi = *(const uint2*)&Vl[cur][vr * 64 + (((4 * kk + 2 + (g >> 1)) ^ h7) * 8) + (g & 1) * 4];
        U8 vbu;
        vbu.u[0] = lo.x; vbu.u[1] = lo.y; vbu.u[2] = hi.x; vbu.u[3] = hi.y;
        oa[dt] = __builtin_amdgcn_mfma_f32_16x16x32_bf16(vbu.v, pa[kk].v, oa[dt], 0, 0, 0);
        ob[dt] = __builtin_amdgcn_mfma_f32_16x16x32_bf16(vbu.v, pb[kk].v, ob[dt], 0, 0, 0);
      }
    }
    __builtin_amdgcn_s_setprio(0);

    __syncthreads();
    cur ^= 1;
  }

  // final l reduce across the 4 lane-copies of each q, then lane-local epilogue
  l_a += __shfl_xor(l_a, 16);
  l_a += __shfl_xor(l_a, 32);
  l_b += __shfl_xor(l_b, 16);
  l_b += __shfl_xor(l_b, 32);
  float inva = 1.0f / l_a, invb = 1.0f / l_b;
  size_t orowA = ((size_t)(b * 1024 + q0 + wave * 16 + l15)) * 1024 + h * 64;
  size_t orowB = orowA + (size_t)128 * 1024;
#pragma unroll
  for (int dt = 0; dt < 4; ++dt) {
    uint2 wa, wb;
    wa.x = cvtpk(oa[dt][0] * inva, oa[dt][1] * inva);
    wa.y = cvtpk(oa[dt][2] * inva, oa[dt][3] * inva);
    *(uint2*)&O[orowA + dt * 16 + g * 4] = wa;
    wb.x = cvtpk(ob[dt][0] * invb, ob[dt][1] * invb);
    wb.y = cvtpk(ob[dt][2] * invb, ob[dt][3] * invb);
    *(uint2*)&O[orowB + dt * 16 + g * 4] = wb;
  }
}

// ---------- launch ----------
extern "C" void kernel_launch(void* const* d_in, const int* in_sizes, int n_in,
                              void* d_out, int out_size, void* d_ws, size_t ws_size,
                              hipStream_t stream) {
  const float* X = (const float*)d_in[0];
  const int* mask = (const int*)d_in[1];
  const float* wq = (const float*)d_in[2];
  const float* bq = (const float*)d_in[3];
  const float* wk = (const float*)d_in[4];
  const float* bk = (const float*)d_in[5];
  const float* wv = (const float*)d_in[6];
  const float* bv = (const float*)d_in[7];
  const float* wo = (const float*)d_in[8];
  const float* bo = (const float*)d_in[9];
  const float* w1 = (const float*)d_in[10];
  const float* b1 = (const float*)d_in[11];
  const float* w2 = (const float*)d_in[12];
  const float* b2 = (const float*)d_in[13];
  const float* ln1a = (const float*)d_in[14];
  const float* ln1b = (const float*)d_in[15];
  const float* ln2a = (const float*)d_in[16];
  const float* ln2b = (const float*)d_in[17];
  float* out = (float*)d_out;
  char* ws = (char*)d_ws;
  const size_t MB = 1024 * 1024;

  // layout (88MB): [0,8) w1_b | [8,16) w2_b | [16,20) wqk_b | [20,22) wv_b |
  // [22,24) wo_b | [24,40) xn (LN1 out -> attn O -> LN2 out) | [40,72) QKb -> hb |
  // [72,88) Vtb
  unsigned short* w1_b = (unsigned short*)(ws + 0 * MB);
  unsigned short* w2_b = (unsigned short*)(ws + 8 * MB);
  unsigned short* wqk_b = (unsigned short*)(ws + 16 * MB);
  unsigned short* wv_b = (unsigned short*)(ws + 20 * MB);
  unsigned short* wo_b = (unsigned short*)(ws + 22 * MB);
  unsigned short* xn = (unsigned short*)(ws + 24 * MB);
  unsigned short* QKb = (unsigned short*)(ws + 40 * MB);
  unsigned short* Vtb = (unsigned short*)(ws + 72 * MB);
  unsigned short* hb = QKb;

  // fused prologue: weight casts + LN1 in one launch (disjoint data, overlaps)
  prep_all<<<20480, 256, 0, stream>>>(w1, w2, wq, wk, wv, wo,
                                      w1_b, w2_b, wqk_b, wv_b, wo_b,
                                      X, xn, ln1a, ln1b);

  // fused Q+K projection: QK[token][2048]  (256^2 tile, grid 256 = 1/CU)
  gemm256<0, 1><<<256, 512, 0, stream>>>(xn, wqk_b, bq, bk, 1024, QKb,
                                         8192, 2048, 1024, 1024, 1024);
  // V transposed: Vt[hd][token] = wv @ xn^T + bv (row bias)  (256x128, grid 256)
  gemm256x128<1><<<256, 512, 0, stream>>>(wv_b, xn, bv, nullptr, nullptr, Vtb,
                                          1024, 8192, 1024, 1024, 1024);
  // attention (writes O into xn buffer); 512 blocks x 512 thr = 2 blocks/CU
  attn_fwd9<<<512, 512, 0, stream>>>(QKb, Vtb, mask, xn);
  // out = X + O @ wo^T + bo  (256x128, grid 256)
  gemm256x128<2><<<256, 512, 0, stream>>>(xn, wo_b, bo, X, out, nullptr,
                                          8192, 1024, 1024, 1024, 1024);
  // LN2 (reads out, writes into xn region)
  ln_bf16<<<8192, 256, 0, stream>>>(out, xn, ln2a, ln2b);
  // FFN chunked along hidden dim: h half = [8192][2048] in hb (QKb region)
  for (int hc = 0; hc < 2; ++hc) {
    // h = relu(xn @ w1[hc*2048:(hc+1)*2048]^T + b1[hc*2048:])  (256^2)
    gemm256<1, 0><<<256, 512, 0, stream>>>(xn, w1_b + (size_t)hc * 2048 * 1024,
                                           b1 + hc * 2048, nullptr, 0, hb,
                                           8192, 2048, 1024, 1024, 1024);
    if (hc == 0)  // out = out + b2 + h_half @ w2[:, 0:2048]^T  (256x128)
      gemm256x128<2><<<256, 512, 0, stream>>>(hb, w2_b, b2, out, out, nullptr,
                                              8192, 1024, 2048, 2048, 4096);
    else          // out += h_half @ w2[:, 2048:4096]^T  (256x128)
      gemm256x128<3><<<256, 512, 0, stream>>>(hb, w2_b + 2048, nullptr, nullptr, out, nullptr,
                                              8192, 1024, 2048, 2048, 4096);
  }
}